// Round 16
// baseline (1663.855 us; speedup 1.0000x reference)
//
#include <hip/hip_runtime.h>
#include <math.h>

// Problem dims
static constexpr int Bd = 4, Ld = 16, Cd = 64, Hd = 64, Wd = 64, Fd = 128;
static constexpr int NBLK = 2, NHEAD = 2;
static constexpr int HW = 4096;                 // Hd*Wd
static constexpr float TWO_PI = 6.28318530717958647692f;

typedef __attribute__((ext_vector_type(8))) short bf16x8;
typedef __attribute__((ext_vector_type(4))) float f32x4;
typedef __attribute__((ext_vector_type(16))) float f32x16;
typedef __attribute__((ext_vector_type(4))) unsigned int u32x4;

// Fast tanh-form GELU (stable): err vs exact erf-GELU <= ~3e-4 absolute.
__device__ __forceinline__ float gelu_f(float v) {
    float x2 = v * v;
    float u = v * (0.797884560802865f + 0.0356774081363f * x2);
    float au = fabsf(u);
    float e = __expf(-2.f * au);
    float th = (1.f - e) * __builtin_amdgcn_rcpf(1.f + e);
    th = copysignf(th, u);
    return 0.5f * v * (1.f + th);
}

__device__ __forceinline__ unsigned short bf16c(float f) {
    unsigned int u = __float_as_uint(f);
    unsigned int r = (u + 0x7fffu + ((u >> 16) & 1u)) >> 16;
    return (unsigned short)r;
}
__device__ __forceinline__ float bf2f(unsigned short u) {
    return __uint_as_float((unsigned int)u << 16);
}
__device__ __forceinline__ unsigned int packbf(float r, float i) {
    return (unsigned int)bf16c(r) | ((unsigned int)bf16c(i) << 16);
}
__device__ __forceinline__ bf16x8 bneg(bf16x8 v) {
    u32x4 u = *(u32x4*)&v;
    u = u ^ 0x80008000u;
    return *(bf16x8*)&u;
}

// async global->LDS, 16 bytes per lane. lds dest = wave-uniform base + lane*16.
__device__ __forceinline__ void gl2lds16(const void* g, void* l) {
    __builtin_amdgcn_global_load_lds(
        (const __attribute__((address_space(1))) void*)g,
        (__attribute__((address_space(3))) void*)l, 16, 0, 0);
}

// ===========================================================================
// Prep: bf16 DFT twiddle tables (once per launch).
// ===========================================================================
__global__ void k_prepdft(unsigned short* __restrict__ o) {
    int idx = blockIdx.x * 256 + threadIdx.x;
    if (idx >= 16384) return;
    int sec = idx >> 12, j = idx & 4095;
    int a = j >> 6, b = j & 63;
    float ang = (TWO_PI / 64.f) * (float)((a * b) & 63);
    float sv, cv;
    __sincosf(ang, &sv, &cv);
    float v;
    if (sec == 0) v = cv;
    else if (sec == 1) v = -sv;
    else if (sec == 2) v = cv * (1.f / 64.f);
    else v = -sv * (1.f / 64.f);
    o[idx] = bf16c(v);
}

// ===========================================================================
// Prep per model-block: bf16 Bw/Cw (r,i) [o][c] + gammaT fp32 [fh][o].
// ===========================================================================
__global__ void k_preplru(const float* __restrict__ bwr, const float* __restrict__ bwi,
                          const float* __restrict__ cwr, const float* __restrict__ cwi,
                          const float* __restrict__ gl,
                          unsigned short* __restrict__ wout, float* __restrict__ gamT) {
    int idx = blockIdx.x * 256 + threadIdx.x;
    if (idx < 16384) {
        int sec = idx >> 12, j = idx & 4095;
        const float* s = (sec == 0) ? bwr : (sec == 1) ? bwi : (sec == 2) ? cwr : cwi;
        wout[idx] = bf16c(s[j]);
    } else if (idx < 20480) {
        int j = idx - 16384;
        int fh = j >> 6, o2 = j & 63;
        gamT[j] = __expf(gl[o2 * 64 + fh]);
    }
}

// ===========================================================================
// DFT over h, MFMA. x: [l][c][h][w] fp32 -> X: [l][w][fh][c] packed bf16 u32.
// ===========================================================================
__global__ __launch_bounds__(256) void k_dfthm(const float* __restrict__ x,
                                               unsigned int* __restrict__ X,
                                               const unsigned short* __restrict__ tcb,
                                               const unsigned short* __restrict__ tsb) {
    __shared__ __align__(16) unsigned char smm[49152];  // xpT 32K | tC 8K | tS 8K
    unsigned char* xpT = smm;
    unsigned char* tC = smm + 32768;
    unsigned char* tS = smm + 40960;
    int blk = blockIdx.x;
    int fi = blk >> 4;
    int w0 = (blk & 15) * 4;
    int t = threadIdx.x, lane = t & 63, wv = t >> 6;
    int pl = lane & 15, kg = lane >> 4;
    int l3 = lane >> 3, l7 = lane & 7;

    for (int q = 0; q < 2; ++q) {
        int sg = q * 4 + wv;
        gl2lds16(tcb + (size_t)(sg * 8 + l3) * 64 + (l7 ^ l3) * 8, tC + sg * 1024);
        gl2lds16(tsb + (size_t)(sg * 8 + l3) * 64 + (l7 ^ l3) * 8, tS + sg * 1024);
    }
    const float* xf = x + (size_t)fi * Cd * HW;
    int h = t & 63;
    for (int k = 0; k < 16; ++k) {
        int c = k * 4 + (t >> 6);
        float4 v = *(const float4*)(xf + (size_t)c * HW + h * 64 + w0);
        float vv[4] = {v.x, v.y, v.z, v.w};
#pragma unroll
        for (int q = 0; q < 4; ++q) {
            int pos = q * 64 + c;
            *(unsigned short*)(xpT + pos * 128 + ((h * 2) ^ ((c & 7) << 4))) = bf16c(vv[q]);
        }
    }
    __syncthreads();

    int w = w0 + wv;
    unsigned int* Xw = X + (size_t)fi * 262144 + (size_t)w * 4096;
    for (int half = 0; half < 2; ++half) {
        f32x4 aR[2][4], aI[2][4];
#pragma unroll
        for (int mt = 0; mt < 2; ++mt)
#pragma unroll
            for (int nt = 0; nt < 4; ++nt) { aR[mt][nt] = (f32x4)0.f; aI[mt][nt] = (f32x4)0.f; }
#pragma unroll
        for (int ks = 0; ks < 2; ++ks) {
            int koff = (ks * 64 + kg * 16);
            bf16x8 ac[2], as_[2], b[4];
#pragma unroll
            for (int mt = 0; mt < 2; ++mt) {
                int row = half * 32 + mt * 16 + pl;
                int off = row * 128 + (koff ^ ((pl & 7) << 4));
                ac[mt] = *(const bf16x8*)(tC + off);
                as_[mt] = *(const bf16x8*)(tS + off);
            }
#pragma unroll
            for (int nt = 0; nt < 4; ++nt) {
                int pos = wv * 64 + nt * 16 + pl;
                b[nt] = *(const bf16x8*)(xpT + pos * 128 + (koff ^ ((pl & 7) << 4)));
            }
#pragma unroll
            for (int mt = 0; mt < 2; ++mt)
#pragma unroll
                for (int nt = 0; nt < 4; ++nt) {
                    aR[mt][nt] = __builtin_amdgcn_mfma_f32_16x16x32_bf16(ac[mt], b[nt], aR[mt][nt], 0, 0, 0);
                    aI[mt][nt] = __builtin_amdgcn_mfma_f32_16x16x32_bf16(as_[mt], b[nt], aI[mt][nt], 0, 0, 0);
                }
        }
#pragma unroll
        for (int mt = 0; mt < 2; ++mt)
#pragma unroll
            for (int nt = 0; nt < 4; ++nt) {
                int c = nt * 16 + pl;
#pragma unroll
                for (int r = 0; r < 4; ++r) {
                    int fh = half * 32 + mt * 16 + kg * 4 + r;
                    Xw[fh * 64 + c] = packbf(aR[mt][nt][r], aI[mt][nt][r]);
                }
            }
    }
}

// ===========================================================================
// FUSED LRU mid-section: Bw-mix + bias + gamma + L-recurrence + Cw-mix.
// ===========================================================================
__global__ __launch_bounds__(256) void k_lrumid(unsigned int* __restrict__ X,
                                                const unsigned short* __restrict__ wbr,
                                                const unsigned short* __restrict__ wbi,
                                                const unsigned short* __restrict__ wcr,
                                                const unsigned short* __restrict__ wci,
                                                const float* __restrict__ gamT,
                                                const float* __restrict__ br_g,
                                                const float* __restrict__ bi_g,
                                                const float* __restrict__ plg) {
    __shared__ __align__(16) unsigned char smm[81920];
    unsigned char* inr = smm;
    unsigned char* ini = smm + 8192;
    unsigned char* hre = smm + 16384;
    unsigned char* him = smm + 24576;
    unsigned char* wBR = smm + 32768;
    unsigned char* wBI = smm + 40960;
    unsigned char* wCR = smm + 49152;
    unsigned char* wCI = smm + 57344;
    float* gam = (float*)(smm + 65536);
    int blk = blockIdx.x;
    int b = blk >> 6, s = blk & 63;
    int t = threadIdx.x, lane = t & 63, wv = t >> 6;
    int pj = lane & 15, kg = lane >> 4;
    int l3 = lane >> 3, l7 = lane & 7;

    for (int q = 0; q < 2; ++q) {
        int sg = q * 4 + wv;
        size_t goff = (size_t)(sg * 8 + l3) * 64 + (l7 ^ l3) * 8;
        gl2lds16(wbr + goff, wBR + sg * 1024);
        gl2lds16(wbi + goff, wBI + sg * 1024);
        gl2lds16(wcr + goff, wCR + sg * 1024);
        gl2lds16(wci + goff, wCI + sg * 1024);
    }
    for (int j = t; j < 4096; j += 256) gam[j] = gamT[j];

    float lamr[4][4], lami[4][4];
#pragma unroll
    for (int nt = 0; nt < 4; ++nt) {
        int o = nt * 16 + pj;
#pragma unroll
        for (int r = 0; r < 4; ++r) {
            int fh = wv * 16 + kg * 4 + r;
            float nu = expf(plg[o * 64 + fh]);
            float th = expf(plg[4096 + o * 64 + fh]);
            float mag = expf(-nu);
            float sth, cth;
            sincosf(th, &sth, &cth);
            lamr[nt][r] = mag * cth;
            lami[nt][r] = mag * sth;
        }
    }
    float bRo[4], bIo[4];
#pragma unroll
    for (int nt = 0; nt < 4; ++nt) {
        bRo[nt] = (s == 0) ? br_g[nt * 16 + pj] : 0.f;
        bIo[nt] = (s == 0) ? bi_g[nt * 16 + pj] : 0.f;
    }
    float str[4][4], sti[4][4];
    unsigned int* Xfrm = X + (size_t)b * 16 * 262144 + (size_t)s * 4096;

    for (int l = 0; l < 16; ++l) {
        unsigned int* Xi = Xfrm + (size_t)l * 262144;
        __syncthreads();
        for (int k = 0; k < 4; ++k) {
            int j = k * 256 + t;
            int row = j >> 4, c0 = (j & 15) * 4;
            u32x4 v = *(const u32x4*)(Xi + (size_t)row * 64 + c0);
            unsigned int rw0 = (v.x & 0xffffu) | (v.y << 16);
            unsigned int rw1 = (v.z & 0xffffu) | (v.w << 16);
            unsigned int iw0 = (v.x >> 16) | (v.y & 0xffff0000u);
            unsigned int iw1 = (v.z >> 16) | (v.w & 0xffff0000u);
            int off = row * 128 + ((((c0 >> 3) ^ (row & 7)) << 4) | ((c0 & 7) * 2));
            *(unsigned int*)(inr + off) = rw0;
            *(unsigned int*)(inr + off + 4) = rw1;
            *(unsigned int*)(ini + off) = iw0;
            *(unsigned int*)(ini + off + 4) = iw1;
        }
        __syncthreads();

        f32x4 cR[4], cI[4];
#pragma unroll
        for (int nt = 0; nt < 4; ++nt) { cR[nt] = (f32x4)0.f; cI[nt] = (f32x4)0.f; }
#pragma unroll
        for (int ks = 0; ks < 2; ++ks) {
            int koff = ks * 64 + kg * 16;
            int aoff = (wv * 16 + pj) * 128 + (koff ^ ((pj & 7) << 4));
            bf16x8 ar = *(const bf16x8*)(inr + aoff);
            bf16x8 ai = *(const bf16x8*)(ini + aoff);
            bf16x8 an = bneg(ai);
#pragma unroll
            for (int nt = 0; nt < 4; ++nt) {
                int o = nt * 16 + pj;
                int woff = o * 128 + (koff ^ ((pj & 7) << 4));
                bf16x8 brf = *(const bf16x8*)(wBR + woff);
                bf16x8 bif = *(const bf16x8*)(wBI + woff);
                cR[nt] = __builtin_amdgcn_mfma_f32_16x16x32_bf16(ar, brf, cR[nt], 0, 0, 0);
                cR[nt] = __builtin_amdgcn_mfma_f32_16x16x32_bf16(an, bif, cR[nt], 0, 0, 0);
                cI[nt] = __builtin_amdgcn_mfma_f32_16x16x32_bf16(ar, bif, cI[nt], 0, 0, 0);
                cI[nt] = __builtin_amdgcn_mfma_f32_16x16x32_bf16(ai, brf, cI[nt], 0, 0, 0);
            }
        }
#pragma unroll
        for (int nt = 0; nt < 4; ++nt) {
            int o = nt * 16 + pj;
#pragma unroll
            for (int r = 0; r < 4; ++r) {
                int row = wv * 16 + kg * 4 + r;
                float g = gam[row * 64 + o];
                float vr = (cR[nt][r] + bRo[nt]) * g;
                float vi = (cI[nt][r] + bIo[nt]) * g;
                if (l == 0) {
                    str[nt][r] = vr;
                    sti[nt][r] = vi;
                } else {
                    float nr = lamr[nt][r] * str[nt][r] - lami[nt][r] * sti[nt][r] + vr;
                    float ni = lamr[nt][r] * sti[nt][r] + lami[nt][r] * str[nt][r] + vi;
                    str[nt][r] = nr;
                    sti[nt][r] = ni;
                }
                int hoff = row * 128 + ((((o >> 3) ^ (row & 7)) << 4) | ((o & 7) * 2));
                *(unsigned short*)(hre + hoff) = bf16c(str[nt][r]);
                *(unsigned short*)(him + hoff) = bf16c(sti[nt][r]);
            }
        }
        __syncthreads();

        f32x4 dR[4], dI[4];
#pragma unroll
        for (int nt = 0; nt < 4; ++nt) { dR[nt] = (f32x4)0.f; dI[nt] = (f32x4)0.f; }
#pragma unroll
        for (int ks = 0; ks < 2; ++ks) {
            int koff = ks * 64 + kg * 16;
            int aoff = (wv * 16 + pj) * 128 + (koff ^ ((pj & 7) << 4));
            bf16x8 ar = *(const bf16x8*)(hre + aoff);
            bf16x8 ai = *(const bf16x8*)(him + aoff);
            bf16x8 an = bneg(ai);
#pragma unroll
            for (int nt = 0; nt < 4; ++nt) {
                int o = nt * 16 + pj;
                int woff = o * 128 + (koff ^ ((pj & 7) << 4));
                bf16x8 brf = *(const bf16x8*)(wCR + woff);
                bf16x8 bif = *(const bf16x8*)(wCI + woff);
                dR[nt] = __builtin_amdgcn_mfma_f32_16x16x32_bf16(ar, brf, dR[nt], 0, 0, 0);
                dR[nt] = __builtin_amdgcn_mfma_f32_16x16x32_bf16(an, bif, dR[nt], 0, 0, 0);
                dI[nt] = __builtin_amdgcn_mfma_f32_16x16x32_bf16(ar, bif, dI[nt], 0, 0, 0);
                dI[nt] = __builtin_amdgcn_mfma_f32_16x16x32_bf16(ai, brf, dI[nt], 0, 0, 0);
            }
        }
#pragma unroll
        for (int nt = 0; nt < 4; ++nt) {
            int o = nt * 16 + pj;
#pragma unroll
            for (int r = 0; r < 4; ++r) {
                int row = wv * 16 + kg * 4 + r;
                Xi[(size_t)row * 64 + o] = packbf(dR[nt][r], dI[nt][r]);
            }
        }
    }
}

// ===========================================================================
// Inverse DFT over h (Re only), MFMA + Cb + LayerNorm(H,W) + residual.
// ===========================================================================
__global__ __launch_bounds__(256) void k_idfthm_ln(const unsigned int* __restrict__ X,
                                                   const unsigned short* __restrict__ tic,
                                                   const unsigned short* __restrict__ tis,
                                                   const float* __restrict__ cbr,
                                                   const float* __restrict__ lnw,
                                                   const float* __restrict__ lnb,
                                                   const float* __restrict__ xprev,
                                                   float* __restrict__ xout) {
    __shared__ __align__(16) unsigned char smm[81920];
    unsigned char* SrT = smm;
    unsigned char* SiT = smm + 32768;
    unsigned char* tC = smm + 65536;
    unsigned char* tS = smm + 73728;
    float* y4 = (float*)smm;
    int blk = blockIdx.x;
    int fi = blk >> 4;
    int c0 = (blk & 15) * 4;
    int t = threadIdx.x, lane = t & 63, wv = t >> 6;
    int pl = lane & 15, kg = lane >> 4;
    int l3 = lane >> 3, l7 = lane & 7;

    for (int q = 0; q < 2; ++q) {
        int sg = q * 4 + wv;
        gl2lds16(tic + (size_t)(sg * 8 + l3) * 64 + (l7 ^ l3) * 8, tC + sg * 1024);
        gl2lds16(tis + (size_t)(sg * 8 + l3) * 64 + (l7 ^ l3) * 8, tS + sg * 1024);
    }
    const unsigned int* Xf = X + (size_t)fi * 262144;
    int fh = t & 63;
    for (int k = 0; k < 16; ++k) {
        int w = k * 4 + (t >> 6);
        u32x4 v = *(const u32x4*)(Xf + (size_t)w * 4096 + fh * 64 + c0);
        unsigned int vv[4] = {v.x, v.y, v.z, v.w};
#pragma unroll
        for (int cj = 0; cj < 4; ++cj) {
            int pos2 = w * 4 + cj;
            int off = pos2 * 128 + ((fh * 2) ^ ((pos2 & 7) << 4));
            *(unsigned short*)(SrT + off) = (unsigned short)(vv[cj] & 0xffffu);
            *(unsigned short*)(SiT + off) = (unsigned short)(vv[cj] >> 16);
        }
    }
    __syncthreads();

    f32x4 y[4][4];
#pragma unroll
    for (int mt = 0; mt < 4; ++mt)
#pragma unroll
        for (int nt = 0; nt < 4; ++nt) y[mt][nt] = (f32x4)0.f;
#pragma unroll
    for (int ks = 0; ks < 2; ++ks) {
        int koff = ks * 64 + kg * 16;
        bf16x8 ac[4], as_[4], brf[4], bif[4];
#pragma unroll
        for (int mt = 0; mt < 4; ++mt) {
            int row = mt * 16 + pl;
            int off = row * 128 + (koff ^ ((pl & 7) << 4));
            ac[mt] = *(const bf16x8*)(tC + off);
            as_[mt] = *(const bf16x8*)(tS + off);
        }
#pragma unroll
        for (int nt = 0; nt < 4; ++nt) {
            int pos2 = wv * 64 + nt * 16 + pl;
            int off = pos2 * 128 + (koff ^ ((pl & 7) << 4));
            brf[nt] = *(const bf16x8*)(SrT + off);
            bif[nt] = *(const bf16x8*)(SiT + off);
        }
#pragma unroll
        for (int mt = 0; mt < 4; ++mt)
#pragma unroll
            for (int nt = 0; nt < 4; ++nt) {
                y[mt][nt] = __builtin_amdgcn_mfma_f32_16x16x32_bf16(ac[mt], brf[nt], y[mt][nt], 0, 0, 0);
                y[mt][nt] = __builtin_amdgcn_mfma_f32_16x16x32_bf16(as_[mt], bif[nt], y[mt][nt], 0, 0, 0);
            }
    }
    __syncthreads();

    float cb4[4];
#pragma unroll
    for (int cj = 0; cj < 4; ++cj) cb4[cj] = cbr[c0 + cj];
#pragma unroll
    for (int mt = 0; mt < 4; ++mt)
#pragma unroll
        for (int nt = 0; nt < 4; ++nt) {
            int pos2 = wv * 64 + nt * 16 + pl;
            int w = pos2 >> 2, cj = pos2 & 3;
#pragma unroll
            for (int r = 0; r < 4; ++r) {
                int h = mt * 16 + kg * 4 + r;
                y4[cj * 4232 + h * 66 + w] = y[mt][nt][r] + cb4[cj];
            }
        }
    __syncthreads();

    int w = lane;
    const float* yp = y4 + wv * 4232;
    float s = 0.f, q = 0.f;
    for (int h = 0; h < 64; ++h) {
        float v = yp[h * 66 + w];
        s += v;
        q += v * v;
    }
#pragma unroll
    for (int off = 32; off; off >>= 1) {
        s += __shfl_xor(s, off);
        q += __shfl_xor(q, off);
    }
    float m = s * (1.f / 4096.f);
    float var = q * (1.f / 4096.f) - m * m;
    float rs = rsqrtf(var + 1e-5f);
    int c = c0 + wv;
    const float* xp = xprev + ((size_t)fi * Cd + c) * HW;
    float* xo = xout + ((size_t)fi * Cd + c) * HW;
    for (int h = 0; h < 64; ++h) {
        int p = h * 64 + w;
        xo[p] = (yp[h * 66 + w] - m) * rs * lnw[p] + lnb[p] + xp[p];
    }
}

// ===========================================================================
// LN(H,W) + residual accumulate, channel-planar (final ffn_ln). cobuf bf16.
// ===========================================================================
__global__ __launch_bounds__(256) void k_ln_res(const unsigned short* __restrict__ t_in,
                                                const float* __restrict__ w,
                                                const float* __restrict__ b,
                                                float* __restrict__ dst) {
    __shared__ float red[8];
    int fr = blockIdx.x;
    int t = threadIdx.x;
    const unsigned short* src = t_in + (size_t)fr * HW + t * 16;
    float* d = dst + (size_t)fr * HW + t * 16;
    u32x4 v0 = *(const u32x4*)(src);
    u32x4 v1 = *(const u32x4*)(src + 8);
    float vals[16];
    unsigned int vw[8] = {v0.x, v0.y, v0.z, v0.w, v1.x, v1.y, v1.z, v1.w};
#pragma unroll
    for (int j = 0; j < 8; ++j) {
        vals[j * 2] = bf2f((unsigned short)(vw[j] & 0xffffu));
        vals[j * 2 + 1] = bf2f((unsigned short)(vw[j] >> 16));
    }
    float s = 0.f, sq = 0.f;
#pragma unroll
    for (int j = 0; j < 16; ++j) { s += vals[j]; sq += vals[j] * vals[j]; }
    for (int off = 32; off; off >>= 1) {
        s += __shfl_down(s, off);
        sq += __shfl_down(sq, off);
    }
    int wid = t >> 6;
    if ((t & 63) == 0) { red[wid] = s; red[4 + wid] = sq; }
    __syncthreads();
    s = red[0] + red[1] + red[2] + red[3];
    sq = red[4] + red[5] + red[6] + red[7];
    float m = s * (1.f / 4096.f);
    float var = sq * (1.f / 4096.f) - m * m;
    float rs = rsqrtf(var + 1e-5f);
    const float* wp = w + t * 16;
    const float* bp = b + t * 16;
#pragma unroll
    for (int q4 = 0; q4 < 4; ++q4) {
        float4 wv4 = *(const float4*)(wp + q4 * 4);
        float4 bv4 = *(const float4*)(bp + q4 * 4);
        float4 dv = *(const float4*)(d + q4 * 4);
        dv.x += (vals[q4 * 4 + 0] - m) * rs * wv4.x + bv4.x;
        dv.y += (vals[q4 * 4 + 1] - m) * rs * wv4.y + bv4.y;
        dv.z += (vals[q4 * 4 + 2] - m) * rs * wv4.z + bv4.z;
        dv.w += (vals[q4 * 4 + 3] - m) * rs * wv4.w + bv4.w;
        *(float4*)(d + q4 * 4) = dv;
    }
}

// ===========================================================================
// Weight prep (fp32 -> bf16, MFMA-friendly layouts)
// ===========================================================================
__global__ void k_prep7(const float* __restrict__ w, unsigned short* __restrict__ o) {
    int idx = blockIdx.x * 256 + threadIdx.x;     // tap*8192 + f*64 + c
    if (idx < 49 * 128 * 64) {
        int tap = idx >> 13, rem = idx & 8191, f = rem >> 6, c = rem & 63;
        o[idx] = bf16c(w[(size_t)(f * 64 + c) * 49 + tap]);
    }
}
__global__ void k_prep3(const float* __restrict__ w, unsigned short* __restrict__ o,
                        int nh) {
    int idx = blockIdx.x * 256 + threadIdx.x;
    if (idx < nh * 147456) {
        int head = idx / 147456;
        int rem = idx - head * 147456;
        int tap = rem >> 14, r2 = rem & 16383, f = r2 >> 7, c = r2 & 127;
        o[idx] = bf16c(w[(size_t)head * 147456 + (size_t)(f * 128 + c) * 9 + tap]);
    }
}
__global__ void k_prepcvt(const float* __restrict__ w, unsigned short* __restrict__ o, int n) {
    int idx = blockIdx.x * 256 + threadIdx.x;
    if (idx < n) o[idx] = bf16c(w[idx]);
}

// Channel-planar fp32 -> position-major bf16  ([c][HW] -> [pos][64])
__global__ __launch_bounds__(256) void k_t2p(const float* __restrict__ x,
                                             unsigned short* __restrict__ xT) {
    __shared__ float tile[64][65];
    int blk = blockIdx.x;
    int f = blk >> 6;
    int p0 = (blk & 63) * 64;
    int t = threadIdx.x;
    const float* src = x + (size_t)f * Cd * HW;
    for (int j = t; j < 4096; j += 256) {
        int c = j >> 6, p = j & 63;
        tile[c][p] = src[(size_t)c * HW + p0 + p];
    }
    __syncthreads();
    unsigned short* dst = xT + ((size_t)f * HW + p0) * 64;
    for (int j = t; j < 4096; j += 256) {
        int p = j >> 6, c = j & 63;
        dst[(size_t)p * 64 + c] = bf16c(tile[c][p]);
    }
}

// ===========================================================================
// 7x7 conv, MFMA 32x32x16, dual-bit XOR swizzle. 8 waves, 8 rows/block.
// Wave tile 128 pos x 64 f as 4x2 tiles of 32x32 (acc 128 VGPR).
// Swizzle: granule ^ (xp&7) ^ ((xp>>3 &1)<<2)  (2-way max on 32-lane frags).
// ===========================================================================
__global__ __launch_bounds__(512) void k_conv7m(const unsigned short* __restrict__ xT,
                                                const unsigned short* __restrict__ wb,
                                                const float* __restrict__ bias,
                                                unsigned short* __restrict__ yout) {
    __shared__ __align__(16) unsigned char smm[158208];   // inT 14*8960 | wdbuf 2*16384
    unsigned char* inT = smm;
    unsigned char* wt0 = smm + 125440;
    int blk = blockIdx.x;
    int fi = blk >> 3;
    int y0 = (blk & 7) * 8;
    int t = threadIdx.x, lane = t & 63, wv = t >> 6;
    int l3 = lane >> 3, l7 = lane & 7;

    const unsigned short* xf = xT + (size_t)fi * HW * 64;
    float4 z4 = make_float4(0.f, 0.f, 0.f, 0.f);
    // stage input rows: LDS[r][xp][gd] = src granule gd ^ (xp&7) ^ ((xp>>3&1)<<2)
    for (int idx = wv; idx < 112; idx += 8) {
        int r = idx >> 3, sg = idx & 7;
        int srow = y0 + r - 3;
        unsigned char* dst = inT + r * 8960 + 3 * 128 + sg * 1024;
        if (srow >= 0 && srow < 64) {
            int xp = 3 + sg * 8 + l3;
            int ksw = l7 ^ (xp & 7) ^ (((xp >> 3) & 1) << 2);
            gl2lds16(xf + (size_t)srow * 4096 + (sg * 8 + l3) * 64 + ksw * 8, dst);
        } else {
            *(float4*)(dst + lane * 16) = z4;
        }
    }
    for (int j = t; j < 672; j += 512) {
        int r = j / 48, k = j % 48;
        int xp = (k < 24) ? (k >> 3) : 67 + ((k - 24) >> 3);
        *(float4*)(inT + r * 8960 + xp * 128 + (k & 7) * 16) = z4;
    }
    // weights: LDS[f][gd] = src granule gd ^ (f&7) ^ ((f>>3&1)<<2); f = sg*8+l3
    int ksw_w = l7 ^ l3;
    for (int q = 0; q < 2; ++q) {
        int sg = q * 8 + wv;
        int f = sg * 8 + l3;
        gl2lds16(wb + (size_t)f * 64 + (ksw_w ^ ((sg & 1) << 2)) * 8, wt0 + sg * 1024);
    }
    __syncthreads();

    int wm = wv & 3, wn = wv >> 2;
    int l31 = lane & 31, kh = lane >> 5;
    f32x16 acc[4][2];
#pragma unroll
    for (int mt = 0; mt < 4; ++mt)
#pragma unroll
        for (int nt = 0; nt < 2; ++nt) acc[mt][nt] = (f32x16)0.f;
    int cur = 0;
    for (int tap = 0; tap < 49; ++tap) {
        if (tap + 1 < 49) {
            const unsigned short* g = wb + (size_t)(tap + 1) * 8192;
            unsigned char* wdst = wt0 + (cur ^ 1) * 16384;
            for (int q = 0; q < 2; ++q) {
                int sg = q * 8 + wv;
                int f = sg * 8 + l3;
                gl2lds16(g + (size_t)f * 64 + (ksw_w ^ ((sg & 1) << 2)) * 8, wdst + sg * 1024);
            }
        }
        unsigned char* wcur = wt0 + cur * 16384;
        int ky = tap / 7, kx = tap % 7;
        int fsw = (l31 & 7) ^ (((l31 >> 3) & 1) << 2);
#pragma unroll
        for (int ks = 0; ks < 4; ++ks) {
            int gran = ks * 2 + kh;
            bf16x8 a[4], b[2];
#pragma unroll
            for (int mt = 0; mt < 4; ++mt) {
                int row = wm * 2 + (mt >> 1) + ky;
                int xp = (mt & 1) * 32 + l31 + kx;
                a[mt] = *(const bf16x8*)(inT + row * 8960 + xp * 128 +
                         ((gran ^ (xp & 7) ^ (((xp >> 3) & 1) << 2)) << 4));
            }
#pragma unroll
            for (int nt = 0; nt < 2; ++nt) {
                int f = wn * 64 + nt * 32 + l31;
                b[nt] = *(const bf16x8*)(wcur + f * 128 + ((gran ^ fsw) << 4));
            }
#pragma unroll
            for (int mt = 0; mt < 4; ++mt)
#pragma unroll
                for (int nt = 0; nt < 2; ++nt)
                    acc[mt][nt] = __builtin_amdgcn_mfma_f32_32x32x16_bf16(a[mt], b[nt], acc[mt][nt], 0, 0, 0);
        }
        __syncthreads();
        cur ^= 1;
    }
    unsigned short* yo = yout + ((size_t)fi * HW + (size_t)y0 * 64) * 128;
#pragma unroll
    for (int mt = 0; mt < 4; ++mt) {
        int rowl = wm * 2 + (mt >> 1);
#pragma unroll
        for (int nt = 0; nt < 2; ++nt) {
            int f = wn * 64 + nt * 32 + l31;
            float bs = bias[f];
#pragma unroll
            for (int r = 0; r < 16; ++r) {
                int prow = (r & 3) + 8 * (r >> 2) + 4 * kh;
                int x = (mt & 1) * 32 + prow;
                yo[(size_t)(rowl * 64 + x) * 128 + f] = bf16c(gelu_f(acc[mt][nt][r] + bs));
            }
        }
    }
}

// ===========================================================================
// FUSED 3x3 conv + 1x1 (h1) + gelu + LN partials. 8 waves, 4 rows/block.
// conv7m-style: no pad columns (edge via compile-time predicated selects),
// 2x32KB DMA double-buffered weights, ONE barrier per tap (9 total).
// ===========================================================================
__global__ __launch_bounds__(512) void k_conv3f(const unsigned short* __restrict__ yin,
                                                const unsigned short* __restrict__ wb,
                                                const float* __restrict__ bias3,
                                                const unsigned short* __restrict__ w1,
                                                const float* __restrict__ bias1,
                                                unsigned short* __restrict__ outp2,
                                                float* __restrict__ lnpart) {
    __shared__ __align__(16) unsigned char smm[163840];   // inT 98304 | wdbuf 2*32768
    unsigned char* inT = smm;
    unsigned char* wt0 = smm + 98304;
    int blk = blockIdx.x;
    int fi = blk >> 4;
    int y0 = (blk & 15) * 4;
    int t = threadIdx.x, lane = t & 63, wv = t >> 6;
    int l4 = lane >> 4, l15 = lane & 15;
    const unsigned short* yf = yin + (size_t)fi * HW * 128;
    float4 z4 = make_float4(0.f, 0.f, 0.f, 0.f);
    // stage 6 input rows (y0-1 .. y0+4), cols 0..63, no pads
    for (int seg = wv; seg < 96; seg += 8) {
        int r = seg >> 4, xs = seg & 15;
        int srow = y0 + r - 1;
        int col = xs * 4 + l4;
        unsigned char* dst = inT + r * 16384 + xs * 4 * 256;
        if (srow >= 0 && srow < 64) {
            int gs = l15 ^ (col & 7);
            gl2lds16(yf + ((size_t)(srow * 64 + col) * 128 + gs * 8), dst);
        } else {
            *(float4*)(dst + lane * 16) = z4;
        }
    }
    // weights tap 0
    for (int q = 0; q < 4; ++q) {
        int sg = q * 8 + wv;
        int f = sg * 4 + l4;
        gl2lds16(wb + (size_t)f * 128 + (l15 ^ (f & 7)) * 8, wt0 + sg * 1024);
    }
    __syncthreads();

    int wm = wv & 3, wn = wv >> 2;
    f32x4 acc[4][4];
#pragma unroll
    for (int m = 0; m < 4; ++m)
#pragma unroll
        for (int n = 0; n < 4; ++n) acc[m][n] = (f32x4)0.f;
    int kg = lane >> 4, pl = lane & 15;
    bf16x8 z8 = (bf16x8)(short)0;
    int cur = 0;
#pragma unroll
    for (int tap = 0; tap < 9; ++tap) {
        if (tap + 1 < 9) {
            const unsigned short* g = wb + (size_t)(tap + 1) * 16384;
            unsigned char* wdst = wt0 + (cur ^ 1) * 32768;
            for (int q = 0; q < 4; ++q) {
                int sg = q * 8 + wv;
                int f = sg * 4 + l4;
                gl2lds16(g + (size_t)f * 128 + (l15 ^ (f & 7)) * 8, wdst + sg * 1024);
            }
        }
        unsigned char* wcur = wt0 + cur * 32768;
        const int ky = tap / 3, kx = tap % 3;
        int rbase = (wm + ky) * 16384;
#pragma unroll
        for (int ks = 0; ks < 4; ++ks) {
            bf16x8 a[4], b[4];
#pragma unroll
            for (int m = 0; m < 4; ++m) {
                int col = m * 16 + pl + kx - 1;
                int colc = col;
                if (kx == 0 && m == 0) colc = (col < 0) ? 0 : col;
                if (kx == 2 && m == 3) colc = (col > 63) ? 63 : col;
                a[m] = *(const bf16x8*)(inT + rbase + colc * 256 +
                                        ((ks * 64 + kg * 16) ^ ((colc & 7) << 4)));
                if (kx == 0 && m == 0) a[m] = (pl == 0) ? z8 : a[m];
                if (kx == 2 && m == 3) a[m] = (pl == 15) ? z8 : a[m];
            }
#pragma unroll
            for (int n = 0; n < 4; ++n) {
                int row = wn * 64 + n * 16 + pl;
                b[n] = *(const bf16x8*)(wcur + (size_t)row * 256 +
                                        ((ks * 64 + kg * 16) ^ ((pl & 7) << 4)));
            }
#pragma unroll
            for (int m = 0; m < 4; ++m)
#pragma unroll
                for (int n = 0; n < 4; ++n)
                    acc[m][n] = __builtin_amdgcn_mfma_f32_16x16x32_bf16(a[m], b[n], acc[m][n], 0, 0, 0);
        }
        __syncthreads();
        cur ^= 1;
    }

    // ---- fused 1x1: t -> LDS (inT region dead), stage W1, GEMM ----
    unsigned char* tL = smm;              // [256 pos][128 f] bf16, swz (64K)
    unsigned char* w1L = smm + 65536;     // [128 o][128 f] bf16, swz (32K)
    float (*redS)[64] = (float (*)[64])(smm + 155648);
    float (*redQ)[64] = (float (*)[64])(smm + 157696);
#pragma unroll
    for (int m = 0; m < 4; ++m)
#pragma unroll
        for (int n = 0; n < 4; ++n) {
            int f = wn * 64 + n * 16 + pl;
            float bs = bias3[f];
#pragma unroll
            for (int r = 0; r < 4; ++r) {
                int pos = wm * 64 + m * 16 + kg * 4 + r;
                *(unsigned short*)(tL + (size_t)pos * 256 +
                    ((((f >> 3) ^ (pos & 7)) << 4) | ((f & 7) * 2))) =
                    bf16c(gelu_f(acc[m][n][r] + bs));
            }
        }
    for (int sg = wv; sg < 32; sg += 8) {
        int rr = sg * 4 + l4;
        gl2lds16(w1 + (size_t)rr * 128 + (l15 ^ (rr & 7)) * 8, w1L + sg * 1024);
    }
    __syncthreads();

    f32x4 fa[4][4];
#pragma unroll
    for (int m = 0; m < 4; ++m)
#pragma unroll
        for (int n = 0; n < 4; ++n) fa[m][n] = (f32x4)0.f;
#pragma unroll
    for (int ks = 0; ks < 4; ++ks) {
        bf16x8 a[4], b[4];
#pragma unroll
        for (int m = 0; m < 4; ++m) {
            int row = wm * 64 + m * 16 + pl;
            a[m] = *(const bf16x8*)(tL + (size_t)row * 256 +
                                    ((ks * 64 + kg * 16) ^ ((pl & 7) << 4)));
        }
#pragma unroll
        for (int n = 0; n < 4; ++n) {
            int row = wn * 64 + n * 16 + pl;
            b[n] = *(const bf16x8*)(w1L + (size_t)row * 256 +
                                    ((ks * 64 + kg * 16) ^ ((pl & 7) << 4)));
        }
#pragma unroll
        for (int m = 0; m < 4; ++m)
#pragma unroll
            for (int n = 0; n < 4; ++n)
                fa[m][n] = __builtin_amdgcn_mfma_f32_16x16x32_bf16(a[m], b[n], fa[m][n], 0, 0, 0);
    }
    __syncthreads();

    int slab = blk & 15;
    int p0 = slab * 256;
    unsigned char* oL = smm;
#pragma unroll
    for (int n = 0; n < 4; ++n) {
        int f = wn * 64 + n * 16 + pl;
        float bs = bias1[f];
        float s = 0.f, q = 0.f;
#pragma unroll
        for (int m = 0; m < 4; ++m)
#pragma unroll
            for (int r = 0; r < 4; ++r) {
                float v = gelu_f(fa[m][n][r] + bs);
                int pos = wm * 64 + m * 16 + kg * 4 + r;
                *(unsigned short*)(oL + (size_t)pos * 256 +
                    ((((f >> 3) ^ (pos & 7)) << 4) | ((f & 7) * 2))) = bf16c(v);
                s += v;
                q += v * v;
            }
        s += __shfl_xor(s, 16); s += __shfl_xor(s, 32);
        q += __shfl_xor(q, 16); q += __shfl_xor(q, 32);
        if (kg == 0) { redS[wv][n * 16 + pl] = s; redQ[wv][n * 16 + pl] = q; }
    }
    __syncthreads();
    unsigned char* o0 = (unsigned char*)(outp2 + ((size_t)fi * HW + p0) * 128);
#pragma unroll
    for (int it = 0; it < 8; ++it) {
        int gid = it * 512 + t;
        int pos = gid >> 4, g = gid & 15;
        u32x4 v = *(const u32x4*)(oL + (size_t)pos * 256 + ((g ^ (pos & 7)) << 4));
        *(u32x4*)(o0 + (size_t)pos * 256 + g * 16) = v;
    }
    if (t < 128) {
        int wh = t >> 6, j = t & 63;
        float s = redS[wh * 4][j] + redS[wh * 4 + 1][j] + redS[wh * 4 + 2][j] + redS[wh * 4 + 3][j];
        float q = redQ[wh * 4][j] + redQ[wh * 4 + 1][j] + redQ[wh * 4 + 2][j] + redQ[wh * 4 + 3][j];
        float* lp = lnpart + ((size_t)(fi * 16 + slab) * 128 + t) * 2;
        lp[0] = s;
        lp[1] = q;
    }
}

// ===========================================================================
// LN finalize (16 slab partials) + apply: y += LN(t2)*w + b. t2, y bf16.
// ===========================================================================
__global__ __launch_bounds__(256) void k_lnapply2(const unsigned short* __restrict__ t2,
                                                  const float* __restrict__ lnpart,
                                                  const float* __restrict__ w,
                                                  const float* __restrict__ b,
                                                  unsigned short* __restrict__ y) {
    __shared__ float sm_m[128], sm_r[128];
    int blk = blockIdx.x;
    int fi = blk >> 5, p0 = (blk & 31) * 128;
    int t = threadIdx.x;
    if (t < 128) {
        float s = 0.f, q = 0.f;
        for (int sl = 0; sl < 16; ++sl) {
            const float* lp = lnpart + ((size_t)(fi * 16 + sl) * 128 + t) * 2;
            s += lp[0];
            q += lp[1];
        }
        float m = s * (1.f / 4096.f);
        float var = q * (1.f / 4096.f) - m * m;
        sm_m[t] = m;
        sm_r[t] = rsqrtf(var + 1e-5f);
    }
    __syncthreads();
    int f = t & 127, ph = t >> 7;
    for (int k = ph; k < 128; k += 2) {
        int p = p0 + k;
        size_t idx = ((size_t)fi * HW + p) * 128 + f;
        float v = bf2f(t2[idx]);
        float yv = bf2f(y[idx]);
        y[idx] = bf16c(yv + (v - sm_m[f]) * sm_r[f] * w[p] + b[p]);
    }
}

// ===========================================================================
// 1x1 cout (128->64), MFMA, A=weights -> channel-planar bf16 out via LDS
// repack -> coalesced stores. y bf16 in.
// ===========================================================================
__global__ __launch_bounds__(256) void k_coutm(const unsigned short* __restrict__ yin,
                                               const unsigned short* __restrict__ wt,
                                               const float* __restrict__ bias,
                                               unsigned short* __restrict__ outp) {
    __shared__ __align__(16) unsigned char smm[49152];
    unsigned char* inL = smm;
    unsigned char* wL = smm + 32768;
    int blk = blockIdx.x;
    int fi = blk >> 5;
    int p0 = (blk & 31) * 128;
    int t = threadIdx.x, lane = t & 63, wv = t >> 6;
    int l4 = lane >> 4, l15 = lane & 15;
    for (int sg = wv; sg < 16; sg += 4) {
        int r = sg * 4 + l4;
        gl2lds16(wt + (size_t)r * 128 + (l15 ^ (r & 7)) * 8, wL + sg * 1024);
    }
    const unsigned short* yb = yin + (size_t)fi * HW * 128;
    for (int sg = wv; sg < 32; sg += 4) {
        int pos = sg * 4 + l4;
        gl2lds16(yb + ((size_t)(p0 + pos) * 128 + (l15 ^ (pos & 7)) * 8), inL + sg * 1024);
    }
    __syncthreads();
    int wm = wv & 1, wn = wv >> 1;
    f32x4 acc[2][4];
#pragma unroll
    for (int m = 0; m < 2; ++m)
#pragma unroll
        for (int n = 0; n < 4; ++n) acc[m][n] = (f32x4)0.f;
    int kg = lane >> 4, pl = lane & 15;
#pragma unroll
    for (int ks = 0; ks < 4; ++ks) {
        bf16x8 a[2], b[4];
#pragma unroll
        for (int m = 0; m < 2; ++m) {
            int row = wm * 32 + m * 16 + pl;
            a[m] = *(const bf16x8*)(wL + (size_t)row * 256 +
                                    ((ks * 64 + kg * 16) ^ ((pl & 7) << 4)));
        }
#pragma unroll
        for (int n = 0; n < 4; ++n) {
            int row = wn * 64 + n * 16 + pl;
            b[n] = *(const bf16x8*)(inL + (size_t)row * 256 +
                                    ((ks * 64 + kg * 16) ^ ((pl & 7) << 4)));
        }
#pragma unroll
        for (int m = 0; m < 2; ++m)
#pragma unroll
            for (int n = 0; n < 4; ++n)
                acc[m][n] = __builtin_amdgcn_mfma_f32_16x16x32_bf16(a[m], b[n], acc[m][n], 0, 0, 0);
    }
    __syncthreads();
    unsigned char* oL = smm;
#pragma unroll
    for (int m = 0; m < 2; ++m)
#pragma unroll
        for (int n = 0; n < 4; ++n) {
            int posl = wn * 64 + n * 16 + pl;
#pragma unroll
            for (int r = 0; r < 4; ++r) {
                int c = wm * 32 + m * 16 + kg * 4 + r;
                *(unsigned short*)(oL + (size_t)c * 256 +
                    ((((posl >> 3) ^ (c & 7)) << 4) | ((posl & 7) * 2))) =
                    bf16c(acc[m][n][r] + bias[c]);
            }
        }
    __syncthreads();
#pragma unroll
    for (int it = 0; it < 4; ++it) {
        int gid = it * 256 + t;
        int c = gid >> 4, g = gid & 15;
        u32x4 v = *(const u32x4*)(oL + (size_t)c * 256 + ((g ^ (c & 7)) << 4));
        *(u32x4*)((unsigned char*)(outp + ((size_t)fi * 64 + c) * HW + p0) + g * 16) = v;
    }
}

// ===========================================================================
extern "C" void kernel_launch(void* const* d_in, const int* in_sizes, int n_in,
                              void* d_out, int out_size, void* d_ws, size_t ws_size,
                              hipStream_t stream) {
    (void)in_sizes; (void)n_in; (void)out_size;
    const float* x_in  = (const float*)d_in[0];
    const float* pl    = (const float*)d_in[1];
    const float* pBw_r = (const float*)d_in[2];
    const float* pBw_i = (const float*)d_in[3];
    const float* pBb_r = (const float*)d_in[4];
    const float* pBb_i = (const float*)d_in[5];
    const float* pCw_r = (const float*)d_in[6];
    const float* pCw_i = (const float*)d_in[7];
    const float* pCb_r = (const float*)d_in[8];
    const float* pCb_i = (const float*)d_in[9];
    const float* lruw  = (const float*)d_in[10];
    const float* lrub  = (const float*)d_in[11];
    const float* cinw  = (const float*)d_in[12];
    const float* cinb  = (const float*)d_in[13];
    const float* h3w   = (const float*)d_in[14];
    const float* h3b   = (const float*)d_in[15];
    const float* h1w   = (const float*)d_in[16];
    const float* h1b   = (const float*)d_in[17];
    const float* hlnw  = (const float*)d_in[18];
    const float* hlnb  = (const float*)d_in[19];
    const float* coutw = (const float*)d_in[20];
    const float* coutb = (const float*)d_in[21];
    const float* flnw  = (const float*)d_in[22];
    const float* flnb  = (const float*)d_in[23];
    float* out = (float*)d_out;

    // --- adaptive chunk tier (X bf16: 16.78 MB per LRU batch; FFN 3 MiB/frame) ---
    int FR = 8, LB = 1;
    {
        const int frs[6] = {64, 32, 16, 16, 8, 8};
        const int lbs[6] = {4, 4, 4, 2, 2, 1};
        for (int k = 0; k < 6; ++k) {
            size_t region = (size_t)lbs[k] * 16777216ULL;
            size_t ffn = (size_t)frs[k] * 3145728ULL;
            if (ffn > region) region = ffn;
            size_t needb = region + 1605632ULL + (size_t)frs[k] * 32768ULL + 65536ULL;
            if (needb <= ws_size) { FR = frs[k]; LB = lbs[k]; break; }
        }
    }
    size_t region = (size_t)LB * 16777216ULL;
    {
        size_t ffn = (size_t)FR * 3145728ULL;
        if (ffn > region) region = ffn;
    }
    unsigned char* ws = (unsigned char*)d_ws;
    unsigned int* Xb = (unsigned int*)ws;                                // LB*16.78 MB
    unsigned short* ybuf = (unsigned short*)ws;                          // FR*1 MiB
    unsigned short* t2bf = (unsigned short*)(ws + (size_t)FR * 1048576); // FR*1 MiB
    unsigned short* xT   = (unsigned short*)(ws + (size_t)FR * 2097152); // FR*0.5 MiB
    unsigned short* cobuf = (unsigned short*)(ws + (size_t)FR * 2621440);// FR*0.5 MiB
    unsigned char* wbase = ws + region;
    unsigned short* wb7  = (unsigned short*)(wbase);              //   802,816 B
    unsigned short* wb3  = (unsigned short*)(wbase + 802816);     //   589,824 B
    unsigned short* wb1  = (unsigned short*)(wbase + 1392640);    //    65,536 B
    unsigned short* wbco = (unsigned short*)(wbase + 1458176);    //    16,384 B
    unsigned short* dftT = (unsigned short*)(wbase + 1474560);    //    32,768 B
    unsigned short* lruW = (unsigned short*)(wbase + 1507328);    //    32,768 B
    float* gamT          = (float*)(wbase + 1540096);             //    16,384 B
    float* lnpart        = (float*)(wbase + 1556480);             // FR*32,768 B
    unsigned short* tcb = dftT;
    unsigned short* tsb = dftT + 4096;
    unsigned short* tic = dftT + 8192;
    unsigned short* tis = dftT + 12288;
    unsigned short* wBr = lruW;
    unsigned short* wBi = lruW + 4096;
    unsigned short* wCr = lruW + 8192;
    unsigned short* wCi = lruW + 12288;

    const int NCl = 4 / LB;
    const int NCf = 64 / FR;

    k_prepdft<<<64, 256, 0, stream>>>(dftT);

    for (int i = 0; i < NBLK; ++i) {
        const float* xsrc = (i == 0) ? x_in : out;

        // ---------------- ConvLRULayer (MFMA, half-domain DFT over h) -------
        k_preplru<<<80, 256, 0, stream>>>(pBw_r + (size_t)i * 4096,
                                          pBw_i + (size_t)i * 4096,
                                          pCw_r + (size_t)i * 4096,
                                          pCw_i + (size_t)i * 4096,
                                          pl + (size_t)i * 12288 + 8192, lruW, gamT);
        for (int cc = 0; cc < NCl; ++cc) {
            size_t boff = (size_t)cc * LB * 4194304;
            k_dfthm<<<LB * 256, 256, 0, stream>>>(xsrc + boff, Xb, tcb, tsb);
            k_lrumid<<<LB * 64, 256, 0, stream>>>(Xb, wBr, wBi, wCr, wCi, gamT,
                                                  pBb_r + (size_t)i * 64,
                                                  pBb_i + (size_t)i * 64,
                                                  pl + (size_t)i * 12288);
            k_idfthm_ln<<<LB * 256, 256, 0, stream>>>(Xb, tic, tis,
                                                      pCb_r + (size_t)i * 64,
                                                      lruw + (size_t)i * 4096,
                                                      lrub + (size_t)i * 4096,
                                                      xsrc + boff, out + boff);
        }

        // ---------------- FFN weight prep ----------------
        k_prep7<<<1568, 256, 0, stream>>>(cinw + (size_t)i * 401408, wb7);
        k_prep3<<<1152, 256, 0, stream>>>(h3w + (size_t)i * 2 * 147456, wb3, 2);
        k_prepcvt<<<128, 256, 0, stream>>>(h1w + (size_t)i * 2 * 16384, wb1, 32768);
        k_prepcvt<<<32, 256, 0, stream>>>(coutw + (size_t)i * 8192, wbco, 8192);

        // ---------------- FeedForward (FR-frame chunks) ----------------
        for (int cc = 0; cc < NCf; ++cc) {
            float* xb = out + (size_t)cc * FR * 262144;
            k_t2p<<<FR * 64, 256, 0, stream>>>(xb, xT);
            k_conv7m<<<FR * 8, 512, 0, stream>>>(xT, wb7, cinb + (size_t)i * 128, ybuf);
            for (int j = 0; j < NHEAD; ++j) {
                k_conv3f<<<FR * 16, 512, 0, stream>>>(ybuf, wb3 + (size_t)j * 147456,
                                                      h3b + (size_t)(i * 2 + j) * 128,
                                                      wb1 + (size_t)j * 16384,
                                                      h1b + (size_t)(i * 2 + j) * 128,
                                                      t2bf, lnpart);
                k_lnapply2<<<FR * 32, 256, 0, stream>>>(t2bf, lnpart,
                                                        hlnw + (size_t)(i * 2 + j) * 4096,
                                                        hlnb + (size_t)(i * 2 + j) * 4096,
                                                        ybuf);
            }
            k_coutm<<<FR * 32, 256, 0, stream>>>(ybuf, wbco, coutb + (size_t)i * 64, cobuf);
            k_ln_res<<<FR * 64, 256, 0, stream>>>(cobuf, flnw + (size_t)i * 4096,
                                                  flnb + (size_t)i * 4096, xb);
        }
    }
}

// Round 17
// 1658.801 us; speedup vs baseline: 1.0030x; 1.0030x over previous
//
#include <hip/hip_runtime.h>
#include <math.h>

// Problem dims
static constexpr int Bd = 4, Ld = 16, Cd = 64, Hd = 64, Wd = 64, Fd = 128;
static constexpr int NBLK = 2, NHEAD = 2;
static constexpr int HW = 4096;                 // Hd*Wd
static constexpr float TWO_PI = 6.28318530717958647692f;

typedef __attribute__((ext_vector_type(8))) short bf16x8;
typedef __attribute__((ext_vector_type(4))) float f32x4;
typedef __attribute__((ext_vector_type(16))) float f32x16;
typedef __attribute__((ext_vector_type(4))) unsigned int u32x4;

// Fast tanh-form GELU (stable): err vs exact erf-GELU <= ~3e-4 absolute.
__device__ __forceinline__ float gelu_f(float v) {
    float x2 = v * v;
    float u = v * (0.797884560802865f + 0.0356774081363f * x2);
    float au = fabsf(u);
    float e = __expf(-2.f * au);
    float th = (1.f - e) * __builtin_amdgcn_rcpf(1.f + e);
    th = copysignf(th, u);
    return 0.5f * v * (1.f + th);
}

__device__ __forceinline__ unsigned short bf16c(float f) {
    unsigned int u = __float_as_uint(f);
    unsigned int r = (u + 0x7fffu + ((u >> 16) & 1u)) >> 16;
    return (unsigned short)r;
}
__device__ __forceinline__ float bf2f(unsigned short u) {
    return __uint_as_float((unsigned int)u << 16);
}
__device__ __forceinline__ unsigned int packbf(float r, float i) {
    return (unsigned int)bf16c(r) | ((unsigned int)bf16c(i) << 16);
}
__device__ __forceinline__ bf16x8 bneg(bf16x8 v) {
    u32x4 u = *(u32x4*)&v;
    u = u ^ 0x80008000u;
    return *(bf16x8*)&u;
}

// async global->LDS, 16 bytes per lane. lds dest = wave-uniform base + lane*16.
__device__ __forceinline__ void gl2lds16(const void* g, void* l) {
    __builtin_amdgcn_global_load_lds(
        (const __attribute__((address_space(1))) void*)g,
        (__attribute__((address_space(3))) void*)l, 16, 0, 0);
}

// ===========================================================================
// Prep: bf16 DFT twiddle tables (once per launch).
// ===========================================================================
__global__ void k_prepdft(unsigned short* __restrict__ o) {
    int idx = blockIdx.x * 256 + threadIdx.x;
    if (idx >= 16384) return;
    int sec = idx >> 12, j = idx & 4095;
    int a = j >> 6, b = j & 63;
    float ang = (TWO_PI / 64.f) * (float)((a * b) & 63);
    float sv, cv;
    __sincosf(ang, &sv, &cv);
    float v;
    if (sec == 0) v = cv;
    else if (sec == 1) v = -sv;
    else if (sec == 2) v = cv * (1.f / 64.f);
    else v = -sv * (1.f / 64.f);
    o[idx] = bf16c(v);
}

// ===========================================================================
// Prep per model-block: bf16 Bw/Cw (r,i) [o][c] + gammaT fp32 [fh][o].
// ===========================================================================
__global__ void k_preplru(const float* __restrict__ bwr, const float* __restrict__ bwi,
                          const float* __restrict__ cwr, const float* __restrict__ cwi,
                          const float* __restrict__ gl,
                          unsigned short* __restrict__ wout, float* __restrict__ gamT) {
    int idx = blockIdx.x * 256 + threadIdx.x;
    if (idx < 16384) {
        int sec = idx >> 12, j = idx & 4095;
        const float* s = (sec == 0) ? bwr : (sec == 1) ? bwi : (sec == 2) ? cwr : cwi;
        wout[idx] = bf16c(s[j]);
    } else if (idx < 20480) {
        int j = idx - 16384;
        int fh = j >> 6, o2 = j & 63;
        gamT[j] = __expf(gl[o2 * 64 + fh]);
    }
}

// ===========================================================================
// DFT over h, MFMA. x: [l][c][h][w] fp32 -> X: [l][w][fh][c] packed bf16 u32.
// ===========================================================================
__global__ __launch_bounds__(256) void k_dfthm(const float* __restrict__ x,
                                               unsigned int* __restrict__ X,
                                               const unsigned short* __restrict__ tcb,
                                               const unsigned short* __restrict__ tsb) {
    __shared__ __align__(16) unsigned char smm[49152];  // xpT 32K | tC 8K | tS 8K
    unsigned char* xpT = smm;
    unsigned char* tC = smm + 32768;
    unsigned char* tS = smm + 40960;
    int blk = blockIdx.x;
    int fi = blk >> 4;
    int w0 = (blk & 15) * 4;
    int t = threadIdx.x, lane = t & 63, wv = t >> 6;
    int pl = lane & 15, kg = lane >> 4;
    int l3 = lane >> 3, l7 = lane & 7;

    for (int q = 0; q < 2; ++q) {
        int sg = q * 4 + wv;
        gl2lds16(tcb + (size_t)(sg * 8 + l3) * 64 + (l7 ^ l3) * 8, tC + sg * 1024);
        gl2lds16(tsb + (size_t)(sg * 8 + l3) * 64 + (l7 ^ l3) * 8, tS + sg * 1024);
    }
    const float* xf = x + (size_t)fi * Cd * HW;
    int h = t & 63;
    for (int k = 0; k < 16; ++k) {
        int c = k * 4 + (t >> 6);
        float4 v = *(const float4*)(xf + (size_t)c * HW + h * 64 + w0);
        float vv[4] = {v.x, v.y, v.z, v.w};
#pragma unroll
        for (int q = 0; q < 4; ++q) {
            int pos = q * 64 + c;
            *(unsigned short*)(xpT + pos * 128 + ((h * 2) ^ ((c & 7) << 4))) = bf16c(vv[q]);
        }
    }
    __syncthreads();

    int w = w0 + wv;
    unsigned int* Xw = X + (size_t)fi * 262144 + (size_t)w * 4096;
    for (int half = 0; half < 2; ++half) {
        f32x4 aR[2][4], aI[2][4];
#pragma unroll
        for (int mt = 0; mt < 2; ++mt)
#pragma unroll
            for (int nt = 0; nt < 4; ++nt) { aR[mt][nt] = (f32x4)0.f; aI[mt][nt] = (f32x4)0.f; }
#pragma unroll
        for (int ks = 0; ks < 2; ++ks) {
            int koff = (ks * 64 + kg * 16);
            bf16x8 ac[2], as_[2], b[4];
#pragma unroll
            for (int mt = 0; mt < 2; ++mt) {
                int row = half * 32 + mt * 16 + pl;
                int off = row * 128 + (koff ^ ((pl & 7) << 4));
                ac[mt] = *(const bf16x8*)(tC + off);
                as_[mt] = *(const bf16x8*)(tS + off);
            }
#pragma unroll
            for (int nt = 0; nt < 4; ++nt) {
                int pos = wv * 64 + nt * 16 + pl;
                b[nt] = *(const bf16x8*)(xpT + pos * 128 + (koff ^ ((pl & 7) << 4)));
            }
#pragma unroll
            for (int mt = 0; mt < 2; ++mt)
#pragma unroll
                for (int nt = 0; nt < 4; ++nt) {
                    aR[mt][nt] = __builtin_amdgcn_mfma_f32_16x16x32_bf16(ac[mt], b[nt], aR[mt][nt], 0, 0, 0);
                    aI[mt][nt] = __builtin_amdgcn_mfma_f32_16x16x32_bf16(as_[mt], b[nt], aI[mt][nt], 0, 0, 0);
                }
        }
#pragma unroll
        for (int mt = 0; mt < 2; ++mt)
#pragma unroll
            for (int nt = 0; nt < 4; ++nt) {
                int c = nt * 16 + pl;
#pragma unroll
                for (int r = 0; r < 4; ++r) {
                    int fh = half * 32 + mt * 16 + kg * 4 + r;
                    Xw[fh * 64 + c] = packbf(aR[mt][nt][r], aI[mt][nt][r]);
                }
            }
    }
}

// ===========================================================================
// FUSED LRU mid-section: Bw-mix + bias + gamma + L-recurrence + Cw-mix.
// ===========================================================================
__global__ __launch_bounds__(256) void k_lrumid(unsigned int* __restrict__ X,
                                                const unsigned short* __restrict__ wbr,
                                                const unsigned short* __restrict__ wbi,
                                                const unsigned short* __restrict__ wcr,
                                                const unsigned short* __restrict__ wci,
                                                const float* __restrict__ gamT,
                                                const float* __restrict__ br_g,
                                                const float* __restrict__ bi_g,
                                                const float* __restrict__ plg) {
    __shared__ __align__(16) unsigned char smm[81920];
    unsigned char* inr = smm;
    unsigned char* ini = smm + 8192;
    unsigned char* hre = smm + 16384;
    unsigned char* him = smm + 24576;
    unsigned char* wBR = smm + 32768;
    unsigned char* wBI = smm + 40960;
    unsigned char* wCR = smm + 49152;
    unsigned char* wCI = smm + 57344;
    float* gam = (float*)(smm + 65536);
    int blk = blockIdx.x;
    int b = blk >> 6, s = blk & 63;
    int t = threadIdx.x, lane = t & 63, wv = t >> 6;
    int pj = lane & 15, kg = lane >> 4;
    int l3 = lane >> 3, l7 = lane & 7;

    for (int q = 0; q < 2; ++q) {
        int sg = q * 4 + wv;
        size_t goff = (size_t)(sg * 8 + l3) * 64 + (l7 ^ l3) * 8;
        gl2lds16(wbr + goff, wBR + sg * 1024);
        gl2lds16(wbi + goff, wBI + sg * 1024);
        gl2lds16(wcr + goff, wCR + sg * 1024);
        gl2lds16(wci + goff, wCI + sg * 1024);
    }
    for (int j = t; j < 4096; j += 256) gam[j] = gamT[j];

    float lamr[4][4], lami[4][4];
#pragma unroll
    for (int nt = 0; nt < 4; ++nt) {
        int o = nt * 16 + pj;
#pragma unroll
        for (int r = 0; r < 4; ++r) {
            int fh = wv * 16 + kg * 4 + r;
            float nu = expf(plg[o * 64 + fh]);
            float th = expf(plg[4096 + o * 64 + fh]);
            float mag = expf(-nu);
            float sth, cth;
            sincosf(th, &sth, &cth);
            lamr[nt][r] = mag * cth;
            lami[nt][r] = mag * sth;
        }
    }
    float bRo[4], bIo[4];
#pragma unroll
    for (int nt = 0; nt < 4; ++nt) {
        bRo[nt] = (s == 0) ? br_g[nt * 16 + pj] : 0.f;
        bIo[nt] = (s == 0) ? bi_g[nt * 16 + pj] : 0.f;
    }
    float str[4][4], sti[4][4];
    unsigned int* Xfrm = X + (size_t)b * 16 * 262144 + (size_t)s * 4096;

    for (int l = 0; l < 16; ++l) {
        unsigned int* Xi = Xfrm + (size_t)l * 262144;
        __syncthreads();
        for (int k = 0; k < 4; ++k) {
            int j = k * 256 + t;
            int row = j >> 4, c0 = (j & 15) * 4;
            u32x4 v = *(const u32x4*)(Xi + (size_t)row * 64 + c0);
            unsigned int rw0 = (v.x & 0xffffu) | (v.y << 16);
            unsigned int rw1 = (v.z & 0xffffu) | (v.w << 16);
            unsigned int iw0 = (v.x >> 16) | (v.y & 0xffff0000u);
            unsigned int iw1 = (v.z >> 16) | (v.w & 0xffff0000u);
            int off = row * 128 + ((((c0 >> 3) ^ (row & 7)) << 4) | ((c0 & 7) * 2));
            *(unsigned int*)(inr + off) = rw0;
            *(unsigned int*)(inr + off + 4) = rw1;
            *(unsigned int*)(ini + off) = iw0;
            *(unsigned int*)(ini + off + 4) = iw1;
        }
        __syncthreads();

        f32x4 cR[4], cI[4];
#pragma unroll
        for (int nt = 0; nt < 4; ++nt) { cR[nt] = (f32x4)0.f; cI[nt] = (f32x4)0.f; }
#pragma unroll
        for (int ks = 0; ks < 2; ++ks) {
            int koff = ks * 64 + kg * 16;
            int aoff = (wv * 16 + pj) * 128 + (koff ^ ((pj & 7) << 4));
            bf16x8 ar = *(const bf16x8*)(inr + aoff);
            bf16x8 ai = *(const bf16x8*)(ini + aoff);
            bf16x8 an = bneg(ai);
#pragma unroll
            for (int nt = 0; nt < 4; ++nt) {
                int o = nt * 16 + pj;
                int woff = o * 128 + (koff ^ ((pj & 7) << 4));
                bf16x8 brf = *(const bf16x8*)(wBR + woff);
                bf16x8 bif = *(const bf16x8*)(wBI + woff);
                cR[nt] = __builtin_amdgcn_mfma_f32_16x16x32_bf16(ar, brf, cR[nt], 0, 0, 0);
                cR[nt] = __builtin_amdgcn_mfma_f32_16x16x32_bf16(an, bif, cR[nt], 0, 0, 0);
                cI[nt] = __builtin_amdgcn_mfma_f32_16x16x32_bf16(ar, bif, cI[nt], 0, 0, 0);
                cI[nt] = __builtin_amdgcn_mfma_f32_16x16x32_bf16(ai, brf, cI[nt], 0, 0, 0);
            }
        }
#pragma unroll
        for (int nt = 0; nt < 4; ++nt) {
            int o = nt * 16 + pj;
#pragma unroll
            for (int r = 0; r < 4; ++r) {
                int row = wv * 16 + kg * 4 + r;
                float g = gam[row * 64 + o];
                float vr = (cR[nt][r] + bRo[nt]) * g;
                float vi = (cI[nt][r] + bIo[nt]) * g;
                if (l == 0) {
                    str[nt][r] = vr;
                    sti[nt][r] = vi;
                } else {
                    float nr = lamr[nt][r] * str[nt][r] - lami[nt][r] * sti[nt][r] + vr;
                    float ni = lamr[nt][r] * sti[nt][r] + lami[nt][r] * str[nt][r] + vi;
                    str[nt][r] = nr;
                    sti[nt][r] = ni;
                }
                int hoff = row * 128 + ((((o >> 3) ^ (row & 7)) << 4) | ((o & 7) * 2));
                *(unsigned short*)(hre + hoff) = bf16c(str[nt][r]);
                *(unsigned short*)(him + hoff) = bf16c(sti[nt][r]);
            }
        }
        __syncthreads();

        f32x4 dR[4], dI[4];
#pragma unroll
        for (int nt = 0; nt < 4; ++nt) { dR[nt] = (f32x4)0.f; dI[nt] = (f32x4)0.f; }
#pragma unroll
        for (int ks = 0; ks < 2; ++ks) {
            int koff = ks * 64 + kg * 16;
            int aoff = (wv * 16 + pj) * 128 + (koff ^ ((pj & 7) << 4));
            bf16x8 ar = *(const bf16x8*)(hre + aoff);
            bf16x8 ai = *(const bf16x8*)(him + aoff);
            bf16x8 an = bneg(ai);
#pragma unroll
            for (int nt = 0; nt < 4; ++nt) {
                int o = nt * 16 + pj;
                int woff = o * 128 + (koff ^ ((pj & 7) << 4));
                bf16x8 brf = *(const bf16x8*)(wCR + woff);
                bf16x8 bif = *(const bf16x8*)(wCI + woff);
                dR[nt] = __builtin_amdgcn_mfma_f32_16x16x32_bf16(ar, brf, dR[nt], 0, 0, 0);
                dR[nt] = __builtin_amdgcn_mfma_f32_16x16x32_bf16(an, bif, dR[nt], 0, 0, 0);
                dI[nt] = __builtin_amdgcn_mfma_f32_16x16x32_bf16(ar, bif, dI[nt], 0, 0, 0);
                dI[nt] = __builtin_amdgcn_mfma_f32_16x16x32_bf16(ai, brf, dI[nt], 0, 0, 0);
            }
        }
#pragma unroll
        for (int nt = 0; nt < 4; ++nt) {
            int o = nt * 16 + pj;
#pragma unroll
            for (int r = 0; r < 4; ++r) {
                int row = wv * 16 + kg * 4 + r;
                Xi[(size_t)row * 64 + o] = packbf(dR[nt][r], dI[nt][r]);
            }
        }
    }
}

// ===========================================================================
// Inverse DFT over h (Re only), MFMA + Cb + LayerNorm(H,W) + residual.
// ===========================================================================
__global__ __launch_bounds__(256) void k_idfthm_ln(const unsigned int* __restrict__ X,
                                                   const unsigned short* __restrict__ tic,
                                                   const unsigned short* __restrict__ tis,
                                                   const float* __restrict__ cbr,
                                                   const float* __restrict__ lnw,
                                                   const float* __restrict__ lnb,
                                                   const float* __restrict__ xprev,
                                                   float* __restrict__ xout) {
    __shared__ __align__(16) unsigned char smm[81920];
    unsigned char* SrT = smm;
    unsigned char* SiT = smm + 32768;
    unsigned char* tC = smm + 65536;
    unsigned char* tS = smm + 73728;
    float* y4 = (float*)smm;
    int blk = blockIdx.x;
    int fi = blk >> 4;
    int c0 = (blk & 15) * 4;
    int t = threadIdx.x, lane = t & 63, wv = t >> 6;
    int pl = lane & 15, kg = lane >> 4;
    int l3 = lane >> 3, l7 = lane & 7;

    for (int q = 0; q < 2; ++q) {
        int sg = q * 4 + wv;
        gl2lds16(tic + (size_t)(sg * 8 + l3) * 64 + (l7 ^ l3) * 8, tC + sg * 1024);
        gl2lds16(tis + (size_t)(sg * 8 + l3) * 64 + (l7 ^ l3) * 8, tS + sg * 1024);
    }
    const unsigned int* Xf = X + (size_t)fi * 262144;
    int fh = t & 63;
    for (int k = 0; k < 16; ++k) {
        int w = k * 4 + (t >> 6);
        u32x4 v = *(const u32x4*)(Xf + (size_t)w * 4096 + fh * 64 + c0);
        unsigned int vv[4] = {v.x, v.y, v.z, v.w};
#pragma unroll
        for (int cj = 0; cj < 4; ++cj) {
            int pos2 = w * 4 + cj;
            int off = pos2 * 128 + ((fh * 2) ^ ((pos2 & 7) << 4));
            *(unsigned short*)(SrT + off) = (unsigned short)(vv[cj] & 0xffffu);
            *(unsigned short*)(SiT + off) = (unsigned short)(vv[cj] >> 16);
        }
    }
    __syncthreads();

    f32x4 y[4][4];
#pragma unroll
    for (int mt = 0; mt < 4; ++mt)
#pragma unroll
        for (int nt = 0; nt < 4; ++nt) y[mt][nt] = (f32x4)0.f;
#pragma unroll
    for (int ks = 0; ks < 2; ++ks) {
        int koff = ks * 64 + kg * 16;
        bf16x8 ac[4], as_[4], brf[4], bif[4];
#pragma unroll
        for (int mt = 0; mt < 4; ++mt) {
            int row = mt * 16 + pl;
            int off = row * 128 + (koff ^ ((pl & 7) << 4));
            ac[mt] = *(const bf16x8*)(tC + off);
            as_[mt] = *(const bf16x8*)(tS + off);
        }
#pragma unroll
        for (int nt = 0; nt < 4; ++nt) {
            int pos2 = wv * 64 + nt * 16 + pl;
            int off = pos2 * 128 + (koff ^ ((pl & 7) << 4));
            brf[nt] = *(const bf16x8*)(SrT + off);
            bif[nt] = *(const bf16x8*)(SiT + off);
        }
#pragma unroll
        for (int mt = 0; mt < 4; ++mt)
#pragma unroll
            for (int nt = 0; nt < 4; ++nt) {
                y[mt][nt] = __builtin_amdgcn_mfma_f32_16x16x32_bf16(ac[mt], brf[nt], y[mt][nt], 0, 0, 0);
                y[mt][nt] = __builtin_amdgcn_mfma_f32_16x16x32_bf16(as_[mt], bif[nt], y[mt][nt], 0, 0, 0);
            }
    }
    __syncthreads();

    float cb4[4];
#pragma unroll
    for (int cj = 0; cj < 4; ++cj) cb4[cj] = cbr[c0 + cj];
#pragma unroll
    for (int mt = 0; mt < 4; ++mt)
#pragma unroll
        for (int nt = 0; nt < 4; ++nt) {
            int pos2 = wv * 64 + nt * 16 + pl;
            int w = pos2 >> 2, cj = pos2 & 3;
#pragma unroll
            for (int r = 0; r < 4; ++r) {
                int h = mt * 16 + kg * 4 + r;
                y4[cj * 4232 + h * 66 + w] = y[mt][nt][r] + cb4[cj];
            }
        }
    __syncthreads();

    int w = lane;
    const float* yp = y4 + wv * 4232;
    float s = 0.f, q = 0.f;
    for (int h = 0; h < 64; ++h) {
        float v = yp[h * 66 + w];
        s += v;
        q += v * v;
    }
#pragma unroll
    for (int off = 32; off; off >>= 1) {
        s += __shfl_xor(s, off);
        q += __shfl_xor(q, off);
    }
    float m = s * (1.f / 4096.f);
    float var = q * (1.f / 4096.f) - m * m;
    float rs = rsqrtf(var + 1e-5f);
    int c = c0 + wv;
    const float* xp = xprev + ((size_t)fi * Cd + c) * HW;
    float* xo = xout + ((size_t)fi * Cd + c) * HW;
    for (int h = 0; h < 64; ++h) {
        int p = h * 64 + w;
        xo[p] = (yp[h * 66 + w] - m) * rs * lnw[p] + lnb[p] + xp[p];
    }
}

// ===========================================================================
// LN(H,W) + residual accumulate, channel-planar (final ffn_ln). cobuf bf16.
// ===========================================================================
__global__ __launch_bounds__(256) void k_ln_res(const unsigned short* __restrict__ t_in,
                                                const float* __restrict__ w,
                                                const float* __restrict__ b,
                                                float* __restrict__ dst) {
    __shared__ float red[8];
    int fr = blockIdx.x;
    int t = threadIdx.x;
    const unsigned short* src = t_in + (size_t)fr * HW + t * 16;
    float* d = dst + (size_t)fr * HW + t * 16;
    u32x4 v0 = *(const u32x4*)(src);
    u32x4 v1 = *(const u32x4*)(src + 8);
    float vals[16];
    unsigned int vw[8] = {v0.x, v0.y, v0.z, v0.w, v1.x, v1.y, v1.z, v1.w};
#pragma unroll
    for (int j = 0; j < 8; ++j) {
        vals[j * 2] = bf2f((unsigned short)(vw[j] & 0xffffu));
        vals[j * 2 + 1] = bf2f((unsigned short)(vw[j] >> 16));
    }
    float s = 0.f, sq = 0.f;
#pragma unroll
    for (int j = 0; j < 16; ++j) { s += vals[j]; sq += vals[j] * vals[j]; }
    for (int off = 32; off; off >>= 1) {
        s += __shfl_down(s, off);
        sq += __shfl_down(sq, off);
    }
    int wid = t >> 6;
    if ((t & 63) == 0) { red[wid] = s; red[4 + wid] = sq; }
    __syncthreads();
    s = red[0] + red[1] + red[2] + red[3];
    sq = red[4] + red[5] + red[6] + red[7];
    float m = s * (1.f / 4096.f);
    float var = sq * (1.f / 4096.f) - m * m;
    float rs = rsqrtf(var + 1e-5f);
    const float* wp = w + t * 16;
    const float* bp = b + t * 16;
#pragma unroll
    for (int q4 = 0; q4 < 4; ++q4) {
        float4 wv4 = *(const float4*)(wp + q4 * 4);
        float4 bv4 = *(const float4*)(bp + q4 * 4);
        float4 dv = *(const float4*)(d + q4 * 4);
        dv.x += (vals[q4 * 4 + 0] - m) * rs * wv4.x + bv4.x;
        dv.y += (vals[q4 * 4 + 1] - m) * rs * wv4.y + bv4.y;
        dv.z += (vals[q4 * 4 + 2] - m) * rs * wv4.z + bv4.z;
        dv.w += (vals[q4 * 4 + 3] - m) * rs * wv4.w + bv4.w;
        *(float4*)(d + q4 * 4) = dv;
    }
}

// ===========================================================================
// Weight prep (fp32 -> bf16, MFMA-friendly layouts)
// ===========================================================================
__global__ void k_prep7(const float* __restrict__ w, unsigned short* __restrict__ o) {
    int idx = blockIdx.x * 256 + threadIdx.x;     // tap*8192 + f*64 + c
    if (idx < 49 * 128 * 64) {
        int tap = idx >> 13, rem = idx & 8191, f = rem >> 6, c = rem & 63;
        o[idx] = bf16c(w[(size_t)(f * 64 + c) * 49 + tap]);
    }
}
__global__ void k_prep3(const float* __restrict__ w, unsigned short* __restrict__ o,
                        int nh) {
    int idx = blockIdx.x * 256 + threadIdx.x;
    if (idx < nh * 147456) {
        int head = idx / 147456;
        int rem = idx - head * 147456;
        int tap = rem >> 14, r2 = rem & 16383, f = r2 >> 7, c = r2 & 127;
        o[idx] = bf16c(w[(size_t)head * 147456 + (size_t)(f * 128 + c) * 9 + tap]);
    }
}
__global__ void k_prepcvt(const float* __restrict__ w, unsigned short* __restrict__ o, int n) {
    int idx = blockIdx.x * 256 + threadIdx.x;
    if (idx < n) o[idx] = bf16c(w[idx]);
}

// Channel-planar fp32 -> position-major bf16  ([c][HW] -> [pos][64])
__global__ __launch_bounds__(256) void k_t2p(const float* __restrict__ x,
                                             unsigned short* __restrict__ xT) {
    __shared__ float tile[64][65];
    int blk = blockIdx.x;
    int f = blk >> 6;
    int p0 = (blk & 63) * 64;
    int t = threadIdx.x;
    const float* src = x + (size_t)f * Cd * HW;
    for (int j = t; j < 4096; j += 256) {
        int c = j >> 6, p = j & 63;
        tile[c][p] = src[(size_t)c * HW + p0 + p];
    }
    __syncthreads();
    unsigned short* dst = xT + ((size_t)f * HW + p0) * 64;
    for (int j = t; j < 4096; j += 256) {
        int p = j >> 6, c = j & 63;
        dst[(size_t)p * 64 + c] = bf16c(tile[c][p]);
    }
}

// ===========================================================================
// 7x7 conv, MFMA 32x32x16, single-bit XOR swizzle (gran ^ (row&7)): within
// each 16-lane quarter-wave every granule appears exactly twice -> free 2-way
// (m136). 8 waves, 8 rows/block; wave tile 128 pos x 64 f as 4x2 32x32 tiles.
// ===========================================================================
__global__ __launch_bounds__(512) void k_conv7m(const unsigned short* __restrict__ xT,
                                                const unsigned short* __restrict__ wb,
                                                const float* __restrict__ bias,
                                                unsigned short* __restrict__ yout) {
    __shared__ __align__(16) unsigned char smm[158208];   // inT 14*8960 | wdbuf 2*16384
    unsigned char* inT = smm;
    unsigned char* wt0 = smm + 125440;
    int blk = blockIdx.x;
    int fi = blk >> 3;
    int y0 = (blk & 7) * 8;
    int t = threadIdx.x, lane = t & 63, wv = t >> 6;
    int l3 = lane >> 3, l7 = lane & 7;

    const unsigned short* xf = xT + (size_t)fi * HW * 64;
    float4 z4 = make_float4(0.f, 0.f, 0.f, 0.f);
    int ksw_in = l7 ^ ((3 + l3) & 7);
    for (int idx = wv; idx < 112; idx += 8) {
        int r = idx >> 3, sg = idx & 7;
        int srow = y0 + r - 3;
        unsigned char* dst = inT + r * 8960 + 3 * 128 + sg * 1024;
        if (srow >= 0 && srow < 64) {
            gl2lds16(xf + (size_t)srow * 4096 + (sg * 8 + l3) * 64 + ksw_in * 8, dst);
        } else {
            *(float4*)(dst + lane * 16) = z4;
        }
    }
    for (int j = t; j < 672; j += 512) {
        int r = j / 48, k = j % 48;
        int xp = (k < 24) ? (k >> 3) : 67 + ((k - 24) >> 3);
        *(float4*)(inT + r * 8960 + xp * 128 + (k & 7) * 16) = z4;
    }
    int ksw_w = l7 ^ l3;
    for (int q = 0; q < 2; ++q) {
        int sg = q * 8 + wv;
        int f = sg * 8 + l3;
        gl2lds16(wb + (size_t)f * 64 + ksw_w * 8, wt0 + sg * 1024);
    }
    __syncthreads();

    int wm = wv & 3, wn = wv >> 2;
    int l31 = lane & 31, kh = lane >> 5;
    f32x16 acc[4][2];
#pragma unroll
    for (int mt = 0; mt < 4; ++mt)
#pragma unroll
        for (int nt = 0; nt < 2; ++nt) acc[mt][nt] = (f32x16)0.f;
    int cur = 0;
    for (int tap = 0; tap < 49; ++tap) {
        if (tap + 1 < 49) {
            const unsigned short* g = wb + (size_t)(tap + 1) * 8192;
            unsigned char* wdst = wt0 + (cur ^ 1) * 16384;
            for (int q = 0; q < 2; ++q) {
                int sg = q * 8 + wv;
                int f = sg * 8 + l3;
                gl2lds16(g + (size_t)f * 64 + ksw_w * 8, wdst + sg * 1024);
            }
        }
        unsigned char* wcur = wt0 + cur * 16384;
        int ky = tap / 7, kx = tap % 7;
#pragma unroll
        for (int ks = 0; ks < 4; ++ks) {
            int gran = ks * 2 + kh;
            bf16x8 a[4], b[2];
#pragma unroll
            for (int mt = 0; mt < 4; ++mt) {
                int row = wm * 2 + (mt >> 1) + ky;
                int xp = (mt & 1) * 32 + l31 + kx;
                a[mt] = *(const bf16x8*)(inT + row * 8960 + xp * 128 +
                                         ((gran ^ (xp & 7)) << 4));
            }
#pragma unroll
            for (int nt = 0; nt < 2; ++nt) {
                int f = wn * 64 + nt * 32 + l31;
                b[nt] = *(const bf16x8*)(wcur + f * 128 + ((gran ^ (f & 7)) << 4));
            }
#pragma unroll
            for (int mt = 0; mt < 4; ++mt)
#pragma unroll
                for (int nt = 0; nt < 2; ++nt)
                    acc[mt][nt] = __builtin_amdgcn_mfma_f32_32x32x16_bf16(a[mt], b[nt], acc[mt][nt], 0, 0, 0);
        }
        __syncthreads();
        cur ^= 1;
    }
    unsigned short* yo = yout + ((size_t)fi * HW + (size_t)y0 * 64) * 128;
#pragma unroll
    for (int mt = 0; mt < 4; ++mt) {
        int rowl = wm * 2 + (mt >> 1);
#pragma unroll
        for (int nt = 0; nt < 2; ++nt) {
            int f = wn * 64 + nt * 32 + l31;
            float bs = bias[f];
#pragma unroll
            for (int r = 0; r < 16; ++r) {
                int prow = (r & 3) + 8 * (r >> 2) + 4 * kh;
                int x = (mt & 1) * 32 + prow;
                yo[(size_t)(rowl * 64 + x) * 128 + f] = bf16c(gelu_f(acc[mt][nt][r] + bs));
            }
        }
    }
}

// ===========================================================================
// FUSED 3x3 conv + 1x1 (h1) + gelu + LN partials. 8 waves, 4 rows/block.
// conv7m-style: no pad columns (edge via compile-time predicated selects),
// 2x32KB DMA double-buffered weights, ONE barrier per tap (9 total).
// ===========================================================================
__global__ __launch_bounds__(512) void k_conv3f(const unsigned short* __restrict__ yin,
                                                const unsigned short* __restrict__ wb,
                                                const float* __restrict__ bias3,
                                                const unsigned short* __restrict__ w1,
                                                const float* __restrict__ bias1,
                                                unsigned short* __restrict__ outp2,
                                                float* __restrict__ lnpart) {
    __shared__ __align__(16) unsigned char smm[163840];   // inT 98304 | wdbuf 2*32768
    unsigned char* inT = smm;
    unsigned char* wt0 = smm + 98304;
    int blk = blockIdx.x;
    int fi = blk >> 4;
    int y0 = (blk & 15) * 4;
    int t = threadIdx.x, lane = t & 63, wv = t >> 6;
    int l4 = lane >> 4, l15 = lane & 15;
    const unsigned short* yf = yin + (size_t)fi * HW * 128;
    float4 z4 = make_float4(0.f, 0.f, 0.f, 0.f);
    // stage 6 input rows (y0-1 .. y0+4), cols 0..63, no pads
    for (int seg = wv; seg < 96; seg += 8) {
        int r = seg >> 4, xs = seg & 15;
        int srow = y0 + r - 1;
        int col = xs * 4 + l4;
        unsigned char* dst = inT + r * 16384 + xs * 4 * 256;
        if (srow >= 0 && srow < 64) {
            int gs = l15 ^ (col & 7);
            gl2lds16(yf + ((size_t)(srow * 64 + col) * 128 + gs * 8), dst);
        } else {
            *(float4*)(dst + lane * 16) = z4;
        }
    }
    // weights tap 0
    for (int q = 0; q < 4; ++q) {
        int sg = q * 8 + wv;
        int f = sg * 4 + l4;
        gl2lds16(wb + (size_t)f * 128 + (l15 ^ (f & 7)) * 8, wt0 + sg * 1024);
    }
    __syncthreads();

    int wm = wv & 3, wn = wv >> 2;
    f32x4 acc[4][4];
#pragma unroll
    for (int m = 0; m < 4; ++m)
#pragma unroll
        for (int n = 0; n < 4; ++n) acc[m][n] = (f32x4)0.f;
    int kg = lane >> 4, pl = lane & 15;
    bf16x8 z8 = (bf16x8)(short)0;
    int cur = 0;
#pragma unroll
    for (int tap = 0; tap < 9; ++tap) {
        if (tap + 1 < 9) {
            const unsigned short* g = wb + (size_t)(tap + 1) * 16384;
            unsigned char* wdst = wt0 + (cur ^ 1) * 32768;
            for (int q = 0; q < 4; ++q) {
                int sg = q * 8 + wv;
                int f = sg * 4 + l4;
                gl2lds16(g + (size_t)f * 128 + (l15 ^ (f & 7)) * 8, wdst + sg * 1024);
            }
        }
        unsigned char* wcur = wt0 + cur * 32768;
        const int ky = tap / 3, kx = tap % 3;
        int rbase = (wm + ky) * 16384;
#pragma unroll
        for (int ks = 0; ks < 4; ++ks) {
            bf16x8 a[4], b[4];
#pragma unroll
            for (int m = 0; m < 4; ++m) {
                int col = m * 16 + pl + kx - 1;
                int colc = col;
                if (kx == 0 && m == 0) colc = (col < 0) ? 0 : col;
                if (kx == 2 && m == 3) colc = (col > 63) ? 63 : col;
                a[m] = *(const bf16x8*)(inT + rbase + colc * 256 +
                                        ((ks * 64 + kg * 16) ^ ((colc & 7) << 4)));
                if (kx == 0 && m == 0) a[m] = (pl == 0) ? z8 : a[m];
                if (kx == 2 && m == 3) a[m] = (pl == 15) ? z8 : a[m];
            }
#pragma unroll
            for (int n = 0; n < 4; ++n) {
                int row = wn * 64 + n * 16 + pl;
                b[n] = *(const bf16x8*)(wcur + (size_t)row * 256 +
                                        ((ks * 64 + kg * 16) ^ ((pl & 7) << 4)));
            }
#pragma unroll
            for (int m = 0; m < 4; ++m)
#pragma unroll
                for (int n = 0; n < 4; ++n)
                    acc[m][n] = __builtin_amdgcn_mfma_f32_16x16x32_bf16(a[m], b[n], acc[m][n], 0, 0, 0);
        }
        __syncthreads();
        cur ^= 1;
    }

    // ---- fused 1x1: t -> LDS (inT region dead), stage W1, GEMM ----
    unsigned char* tL = smm;              // [256 pos][128 f] bf16, swz (64K)
    unsigned char* w1L = smm + 65536;     // [128 o][128 f] bf16, swz (32K)
    float (*redS)[64] = (float (*)[64])(smm + 155648);
    float (*redQ)[64] = (float (*)[64])(smm + 157696);
#pragma unroll
    for (int m = 0; m < 4; ++m)
#pragma unroll
        for (int n = 0; n < 4; ++n) {
            int f = wn * 64 + n * 16 + pl;
            float bs = bias3[f];
#pragma unroll
            for (int r = 0; r < 4; ++r) {
                int pos = wm * 64 + m * 16 + kg * 4 + r;
                *(unsigned short*)(tL + (size_t)pos * 256 +
                    ((((f >> 3) ^ (pos & 7)) << 4) | ((f & 7) * 2))) =
                    bf16c(gelu_f(acc[m][n][r] + bs));
            }
        }
    for (int sg = wv; sg < 32; sg += 8) {
        int rr = sg * 4 + l4;
        gl2lds16(w1 + (size_t)rr * 128 + (l15 ^ (rr & 7)) * 8, w1L + sg * 1024);
    }
    __syncthreads();

    f32x4 fa[4][4];
#pragma unroll
    for (int m = 0; m < 4; ++m)
#pragma unroll
        for (int n = 0; n < 4; ++n) fa[m][n] = (f32x4)0.f;
#pragma unroll
    for (int ks = 0; ks < 4; ++ks) {
        bf16x8 a[4], b[4];
#pragma unroll
        for (int m = 0; m < 4; ++m) {
            int row = wm * 64 + m * 16 + pl;
            a[m] = *(const bf16x8*)(tL + (size_t)row * 256 +
                                    ((ks * 64 + kg * 16) ^ ((pl & 7) << 4)));
        }
#pragma unroll
        for (int n = 0; n < 4; ++n) {
            int row = wn * 64 + n * 16 + pl;
            b[n] = *(const bf16x8*)(w1L + (size_t)row * 256 +
                                    ((ks * 64 + kg * 16) ^ ((pl & 7) << 4)));
        }
#pragma unroll
        for (int m = 0; m < 4; ++m)
#pragma unroll
            for (int n = 0; n < 4; ++n)
                fa[m][n] = __builtin_amdgcn_mfma_f32_16x16x32_bf16(a[m], b[n], fa[m][n], 0, 0, 0);
    }
    __syncthreads();

    int slab = blk & 15;
    int p0 = slab * 256;
    unsigned char* oL = smm;
#pragma unroll
    for (int n = 0; n < 4; ++n) {
        int f = wn * 64 + n * 16 + pl;
        float bs = bias1[f];
        float s = 0.f, q = 0.f;
#pragma unroll
        for (int m = 0; m < 4; ++m)
#pragma unroll
            for (int r = 0; r < 4; ++r) {
                float v = gelu_f(fa[m][n][r] + bs);
                int pos = wm * 64 + m * 16 + kg * 4 + r;
                *(unsigned short*)(oL + (size_t)pos * 256 +
                    ((((f >> 3) ^ (pos & 7)) << 4) | ((f & 7) * 2))) = bf16c(v);
                s += v;
                q += v * v;
            }
        s += __shfl_xor(s, 16); s += __shfl_xor(s, 32);
        q += __shfl_xor(q, 16); q += __shfl_xor(q, 32);
        if (kg == 0) { redS[wv][n * 16 + pl] = s; redQ[wv][n * 16 + pl] = q; }
    }
    __syncthreads();
    unsigned char* o0 = (unsigned char*)(outp2 + ((size_t)fi * HW + p0) * 128);
#pragma unroll
    for (int it = 0; it < 8; ++it) {
        int gid = it * 512 + t;
        int pos = gid >> 4, g = gid & 15;
        u32x4 v = *(const u32x4*)(oL + (size_t)pos * 256 + ((g ^ (pos & 7)) << 4));
        *(u32x4*)(o0 + (size_t)pos * 256 + g * 16) = v;
    }
    if (t < 128) {
        int wh = t >> 6, j = t & 63;
        float s = redS[wh * 4][j] + redS[wh * 4 + 1][j] + redS[wh * 4 + 2][j] + redS[wh * 4 + 3][j];
        float q = redQ[wh * 4][j] + redQ[wh * 4 + 1][j] + redQ[wh * 4 + 2][j] + redQ[wh * 4 + 3][j];
        float* lp = lnpart + ((size_t)(fi * 16 + slab) * 128 + t) * 2;
        lp[0] = s;
        lp[1] = q;
    }
}

// ===========================================================================
// LN finalize (16 slab partials) + apply: y += LN(t2)*w + b. t2, y bf16.
// ===========================================================================
__global__ __launch_bounds__(256) void k_lnapply2(const unsigned short* __restrict__ t2,
                                                  const float* __restrict__ lnpart,
                                                  const float* __restrict__ w,
                                                  const float* __restrict__ b,
                                                  unsigned short* __restrict__ y) {
    __shared__ float sm_m[128], sm_r[128];
    int blk = blockIdx.x;
    int fi = blk >> 5, p0 = (blk & 31) * 128;
    int t = threadIdx.x;
    if (t < 128) {
        float s = 0.f, q = 0.f;
        for (int sl = 0; sl < 16; ++sl) {
            const float* lp = lnpart + ((size_t)(fi * 16 + sl) * 128 + t) * 2;
            s += lp[0];
            q += lp[1];
        }
        float m = s * (1.f / 4096.f);
        float var = q * (1.f / 4096.f) - m * m;
        sm_m[t] = m;
        sm_r[t] = rsqrtf(var + 1e-5f);
    }
    __syncthreads();
    int f = t & 127, ph = t >> 7;
    for (int k = ph; k < 128; k += 2) {
        int p = p0 + k;
        size_t idx = ((size_t)fi * HW + p) * 128 + f;
        float v = bf2f(t2[idx]);
        float yv = bf2f(y[idx]);
        y[idx] = bf16c(yv + (v - sm_m[f]) * sm_r[f] * w[p] + b[p]);
    }
}

// ===========================================================================
// 1x1 cout (128->64), MFMA, A=weights -> channel-planar bf16 out via LDS
// repack -> coalesced stores. y bf16 in.
// ===========================================================================
__global__ __launch_bounds__(256) void k_coutm(const unsigned short* __restrict__ yin,
                                               const unsigned short* __restrict__ wt,
                                               const float* __restrict__ bias,
                                               unsigned short* __restrict__ outp) {
    __shared__ __align__(16) unsigned char smm[49152];
    unsigned char* inL = smm;
    unsigned char* wL = smm + 32768;
    int blk = blockIdx.x;
    int fi = blk >> 5;
    int p0 = (blk & 31) * 128;
    int t = threadIdx.x, lane = t & 63, wv = t >> 6;
    int l4 = lane >> 4, l15 = lane & 15;
    for (int sg = wv; sg < 16; sg += 4) {
        int r = sg * 4 + l4;
        gl2lds16(wt + (size_t)r * 128 + (l15 ^ (r & 7)) * 8, wL + sg * 1024);
    }
    const unsigned short* yb = yin + (size_t)fi * HW * 128;
    for (int sg = wv; sg < 32; sg += 4) {
        int pos = sg * 4 + l4;
        gl2lds16(yb + ((size_t)(p0 + pos) * 128 + (l15 ^ (pos & 7)) * 8), inL + sg * 1024);
    }
    __syncthreads();
    int wm = wv & 1, wn = wv >> 1;
    f32x4 acc[2][4];
#pragma unroll
    for (int m = 0; m < 2; ++m)
#pragma unroll
        for (int n = 0; n < 4; ++n) acc[m][n] = (f32x4)0.f;
    int kg = lane >> 4, pl = lane & 15;
#pragma unroll
    for (int ks = 0; ks < 4; ++ks) {
        bf16x8 a[2], b[4];
#pragma unroll
        for (int m = 0; m < 2; ++m) {
            int row = wm * 32 + m * 16 + pl;
            a[m] = *(const bf16x8*)(wL + (size_t)row * 256 +
                                    ((ks * 64 + kg * 16) ^ ((pl & 7) << 4)));
        }
#pragma unroll
        for (int n = 0; n < 4; ++n) {
            int row = wn * 64 + n * 16 + pl;
            b[n] = *(const bf16x8*)(inL + (size_t)row * 256 +
                                    ((ks * 64 + kg * 16) ^ ((pl & 7) << 4)));
        }
#pragma unroll
        for (int m = 0; m < 2; ++m)
#pragma unroll
            for (int n = 0; n < 4; ++n)
                acc[m][n] = __builtin_amdgcn_mfma_f32_16x16x32_bf16(a[m], b[n], acc[m][n], 0, 0, 0);
    }
    __syncthreads();
    unsigned char* oL = smm;
#pragma unroll
    for (int m = 0; m < 2; ++m)
#pragma unroll
        for (int n = 0; n < 4; ++n) {
            int posl = wn * 64 + n * 16 + pl;
#pragma unroll
            for (int r = 0; r < 4; ++r) {
                int c = wm * 32 + m * 16 + kg * 4 + r;
                *(unsigned short*)(oL + (size_t)c * 256 +
                    ((((posl >> 3) ^ (c & 7)) << 4) | ((posl & 7) * 2))) =
                    bf16c(acc[m][n][r] + bias[c]);
            }
        }
    __syncthreads();
#pragma unroll
    for (int it = 0; it < 4; ++it) {
        int gid = it * 256 + t;
        int c = gid >> 4, g = gid & 15;
        u32x4 v = *(const u32x4*)(oL + (size_t)c * 256 + ((g ^ (c & 7)) << 4));
        *(u32x4*)((unsigned char*)(outp + ((size_t)fi * 64 + c) * HW + p0) + g * 16) = v;
    }
}

// ===========================================================================
extern "C" void kernel_launch(void* const* d_in, const int* in_sizes, int n_in,
                              void* d_out, int out_size, void* d_ws, size_t ws_size,
                              hipStream_t stream) {
    (void)in_sizes; (void)n_in; (void)out_size;
    const float* x_in  = (const float*)d_in[0];
    const float* pl    = (const float*)d_in[1];
    const float* pBw_r = (const float*)d_in[2];
    const float* pBw_i = (const float*)d_in[3];
    const float* pBb_r = (const float*)d_in[4];
    const float* pBb_i = (const float*)d_in[5];
    const float* pCw_r = (const float*)d_in[6];
    const float* pCw_i = (const float*)d_in[7];
    const float* pCb_r = (const float*)d_in[8];
    const float* pCb_i = (const float*)d_in[9];
    const float* lruw  = (const float*)d_in[10];
    const float* lrub  = (const float*)d_in[11];
    const float* cinw  = (const float*)d_in[12];
    const float* cinb  = (const float*)d_in[13];
    const float* h3w   = (const float*)d_in[14];
    const float* h3b   = (const float*)d_in[15];
    const float* h1w   = (const float*)d_in[16];
    const float* h1b   = (const float*)d_in[17];
    const float* hlnw  = (const float*)d_in[18];
    const float* hlnb  = (const float*)d_in[19];
    const float* coutw = (const float*)d_in[20];
    const float* coutb = (const float*)d_in[21];
    const float* flnw  = (const float*)d_in[22];
    const float* flnb  = (const float*)d_in[23];
    float* out = (float*)d_out;

    // --- adaptive chunk tier (X bf16: 16.78 MB per LRU batch; FFN 3 MiB/frame) ---
    int FR = 8, LB = 1;
    {
        const int frs[6] = {64, 32, 16, 16, 8, 8};
        const int lbs[6] = {4, 4, 4, 2, 2, 1};
        for (int k = 0; k < 6; ++k) {
            size_t region = (size_t)lbs[k] * 16777216ULL;
            size_t ffn = (size_t)frs[k] * 3145728ULL;
            if (ffn > region) region = ffn;
            size_t needb = region + 1605632ULL + (size_t)frs[k] * 32768ULL + 65536ULL;
            if (needb <= ws_size) { FR = frs[k]; LB = lbs[k]; break; }
        }
    }
    size_t region = (size_t)LB * 16777216ULL;
    {
        size_t ffn = (size_t)FR * 3145728ULL;
        if (ffn > region) region = ffn;
    }
    unsigned char* ws = (unsigned char*)d_ws;
    unsigned int* Xb = (unsigned int*)ws;                                // LB*16.78 MB
    unsigned short* ybuf = (unsigned short*)ws;                          // FR*1 MiB
    unsigned short* t2bf = (unsigned short*)(ws + (size_t)FR * 1048576); // FR*1 MiB
    unsigned short* xT   = (unsigned short*)(ws + (size_t)FR * 2097152); // FR*0.5 MiB
    unsigned short* cobuf = (unsigned short*)(ws + (size_t)FR * 2621440);// FR*0.5 MiB
    unsigned char* wbase = ws + region;
    unsigned short* wb7  = (unsigned short*)(wbase);              //   802,816 B
    unsigned short* wb3  = (unsigned short*)(wbase + 802816);     //   589,824 B
    unsigned short* wb1  = (unsigned short*)(wbase + 1392640);    //    65,536 B
    unsigned short* wbco = (unsigned short*)(wbase + 1458176);    //    16,384 B
    unsigned short* dftT = (unsigned short*)(wbase + 1474560);    //    32,768 B
    unsigned short* lruW = (unsigned short*)(wbase + 1507328);    //    32,768 B
    float* gamT          = (float*)(wbase + 1540096);             //    16,384 B
    float* lnpart        = (float*)(wbase + 1556480);             // FR*32,768 B
    unsigned short* tcb = dftT;
    unsigned short* tsb = dftT + 4096;
    unsigned short* tic = dftT + 8192;
    unsigned short* tis = dftT + 12288;
    unsigned short* wBr = lruW;
    unsigned short* wBi = lruW + 4096;
    unsigned short* wCr = lruW + 8192;
    unsigned short* wCi = lruW + 12288;

    const int NCl = 4 / LB;
    const int NCf = 64 / FR;

    k_prepdft<<<64, 256, 0, stream>>>(dftT);

    for (int i = 0; i < NBLK; ++i) {
        const float* xsrc = (i == 0) ? x_in : out;

        // ---------------- ConvLRULayer (MFMA, half-domain DFT over h) -------
        k_preplru<<<80, 256, 0, stream>>>(pBw_r + (size_t)i * 4096,
                                          pBw_i + (size_t)i * 4096,
                                          pCw_r + (size_t)i * 4096,
                                          pCw_i + (size_t)i * 4096,
                                          pl + (size_t)i * 12288 + 8192, lruW, gamT);
        for (int cc = 0; cc < NCl; ++cc) {
            size_t boff = (size_t)cc * LB * 4194304;
            k_dfthm<<<LB * 256, 256, 0, stream>>>(xsrc + boff, Xb, tcb, tsb);
            k_lrumid<<<LB * 64, 256, 0, stream>>>(Xb, wBr, wBi, wCr, wCi, gamT,
                                                  pBb_r + (size_t)i * 64,
                                                  pBb_i + (size_t)i * 64,
                                                  pl + (size_t)i * 12288);
            k_idfthm_ln<<<LB * 256, 256, 0, stream>>>(Xb, tic, tis,
                                                      pCb_r + (size_t)i * 64,
                                                      lruw + (size_t)i * 4096,
                                                      lrub + (size_t)i * 4096,
                                                      xsrc + boff, out + boff);
        }

        // ---------------- FFN weight prep ----------------
        k_prep7<<<1568, 256, 0, stream>>>(cinw + (size_t)i * 401408, wb7);
        k_prep3<<<1152, 256, 0, stream>>>(h3w + (size_t)i * 2 * 147456, wb3, 2);
        k_prepcvt<<<128, 256, 0, stream>>>(h1w + (size_t)i * 2 * 16384, wb1, 32768);
        k_prepcvt<<<32, 256, 0, stream>>>(coutw + (size_t)i * 8192, wbco, 8192);

        // ---------------- FeedForward (FR-frame chunks) ----------------
        for (int cc = 0; cc < NCf; ++cc) {
            float* xb = out + (size_t)cc * FR * 262144;
            k_t2p<<<FR * 64, 256, 0, stream>>>(xb, xT);
            k_conv7m<<<FR * 8, 512, 0, stream>>>(xT, wb7, cinb + (size_t)i * 128, ybuf);
            for (int j = 0; j < NHEAD; ++j) {
                k_conv3f<<<FR * 16, 512, 0, stream>>>(ybuf, wb3 + (size_t)j * 147456,
                                                      h3b + (size_t)(i * 2 + j) * 128,
                                                      wb1 + (size_t)j * 16384,
                                                      h1b + (size_t)(i * 2 + j) * 128,
                                                      t2bf, lnpart);
                k_lnapply2<<<FR * 32, 256, 0, stream>>>(t2bf, lnpart,
                                                        hlnw + (size_t)(i * 2 + j) * 4096,
                                                        hlnb + (size_t)(i * 2 + j) * 4096,
                                                        ybuf);
            }
            k_coutm<<<FR * 32, 256, 0, stream>>>(ybuf, wbco, coutb + (size_t)i * 64, cobuf);
            k_ln_res<<<FR * 64, 256, 0, stream>>>(cobuf, flnw + (size_t)i * 4096,
                                                  flnb + (size_t)i * 4096, xb);
        }
    }
}

// Round 18
// 1601.198 us; speedup vs baseline: 1.0391x; 1.0360x over previous
//
#include <hip/hip_runtime.h>
#include <math.h>

// Problem dims
static constexpr int Bd = 4, Ld = 16, Cd = 64, Hd = 64, Wd = 64, Fd = 128;
static constexpr int NBLK = 2, NHEAD = 2;
static constexpr int HW = 4096;                 // Hd*Wd
static constexpr float TWO_PI = 6.28318530717958647692f;

typedef __attribute__((ext_vector_type(8))) short bf16x8;
typedef __attribute__((ext_vector_type(4))) float f32x4;
typedef __attribute__((ext_vector_type(4))) unsigned int u32x4;

// Fast tanh-form GELU (stable): err vs exact erf-GELU <= ~3e-4 absolute.
__device__ __forceinline__ float gelu_f(float v) {
    float x2 = v * v;
    float u = v * (0.797884560802865f + 0.0356774081363f * x2);
    float au = fabsf(u);
    float e = __expf(-2.f * au);
    float th = (1.f - e) * __builtin_amdgcn_rcpf(1.f + e);
    th = copysignf(th, u);
    return 0.5f * v * (1.f + th);
}

__device__ __forceinline__ unsigned short bf16c(float f) {
    unsigned int u = __float_as_uint(f);
    unsigned int r = (u + 0x7fffu + ((u >> 16) & 1u)) >> 16;
    return (unsigned short)r;
}
__device__ __forceinline__ float bf2f(unsigned short u) {
    return __uint_as_float((unsigned int)u << 16);
}
__device__ __forceinline__ unsigned int packbf(float r, float i) {
    return (unsigned int)bf16c(r) | ((unsigned int)bf16c(i) << 16);
}
__device__ __forceinline__ bf16x8 bneg(bf16x8 v) {
    u32x4 u = *(u32x4*)&v;
    u = u ^ 0x80008000u;
    return *(bf16x8*)&u;
}

// async global->LDS, 16 bytes per lane. lds dest = wave-uniform base + lane*16.
__device__ __forceinline__ void gl2lds16(const void* g, void* l) {
    __builtin_amdgcn_global_load_lds(
        (const __attribute__((address_space(1))) void*)g,
        (__attribute__((address_space(3))) void*)l, 16, 0, 0);
}

// ===========================================================================
// Prep: bf16 DFT twiddle tables (once per launch).
// ===========================================================================
__global__ void k_prepdft(unsigned short* __restrict__ o) {
    int idx = blockIdx.x * 256 + threadIdx.x;
    if (idx >= 16384) return;
    int sec = idx >> 12, j = idx & 4095;
    int a = j >> 6, b = j & 63;
    float ang = (TWO_PI / 64.f) * (float)((a * b) & 63);
    float sv, cv;
    __sincosf(ang, &sv, &cv);
    float v;
    if (sec == 0) v = cv;
    else if (sec == 1) v = -sv;
    else if (sec == 2) v = cv * (1.f / 64.f);
    else v = -sv * (1.f / 64.f);
    o[idx] = bf16c(v);
}

// ===========================================================================
// Prep per model-block: bf16 Bw/Cw (r,i) [o][c] + gammaT fp32 [fh][o].
// ===========================================================================
__global__ void k_preplru(const float* __restrict__ bwr, const float* __restrict__ bwi,
                          const float* __restrict__ cwr, const float* __restrict__ cwi,
                          const float* __restrict__ gl,
                          unsigned short* __restrict__ wout, float* __restrict__ gamT) {
    int idx = blockIdx.x * 256 + threadIdx.x;
    if (idx < 16384) {
        int sec = idx >> 12, j = idx & 4095;
        const float* s = (sec == 0) ? bwr : (sec == 1) ? bwi : (sec == 2) ? cwr : cwi;
        wout[idx] = bf16c(s[j]);
    } else if (idx < 20480) {
        int j = idx - 16384;
        int fh = j >> 6, o2 = j & 63;
        gamT[j] = __expf(gl[o2 * 64 + fh]);
    }
}

// ===========================================================================
// DFT over h, MFMA. x: [l][c][h][w] fp32 -> X: [l][w][fh][c] packed bf16 u32.
// ===========================================================================
__global__ __launch_bounds__(256) void k_dfthm(const float* __restrict__ x,
                                               unsigned int* __restrict__ X,
                                               const unsigned short* __restrict__ tcb,
                                               const unsigned short* __restrict__ tsb) {
    __shared__ __align__(16) unsigned char smm[49152];  // xpT 32K | tC 8K | tS 8K
    unsigned char* xpT = smm;
    unsigned char* tC = smm + 32768;
    unsigned char* tS = smm + 40960;
    int blk = blockIdx.x;
    int fi = blk >> 4;
    int w0 = (blk & 15) * 4;
    int t = threadIdx.x, lane = t & 63, wv = t >> 6;
    int pl = lane & 15, kg = lane >> 4;
    int l3 = lane >> 3, l7 = lane & 7;

    for (int q = 0; q < 2; ++q) {
        int sg = q * 4 + wv;
        gl2lds16(tcb + (size_t)(sg * 8 + l3) * 64 + (l7 ^ l3) * 8, tC + sg * 1024);
        gl2lds16(tsb + (size_t)(sg * 8 + l3) * 64 + (l7 ^ l3) * 8, tS + sg * 1024);
    }
    const float* xf = x + (size_t)fi * Cd * HW;
    int h = t & 63;
    for (int k = 0; k < 16; ++k) {
        int c = k * 4 + (t >> 6);
        float4 v = *(const float4*)(xf + (size_t)c * HW + h * 64 + w0);
        float vv[4] = {v.x, v.y, v.z, v.w};
#pragma unroll
        for (int q = 0; q < 4; ++q) {
            int pos = q * 64 + c;
            *(unsigned short*)(xpT + pos * 128 + ((h * 2) ^ ((c & 7) << 4))) = bf16c(vv[q]);
        }
    }
    __syncthreads();

    int w = w0 + wv;
    unsigned int* Xw = X + (size_t)fi * 262144 + (size_t)w * 4096;
    for (int half = 0; half < 2; ++half) {
        f32x4 aR[2][4], aI[2][4];
#pragma unroll
        for (int mt = 0; mt < 2; ++mt)
#pragma unroll
            for (int nt = 0; nt < 4; ++nt) { aR[mt][nt] = (f32x4)0.f; aI[mt][nt] = (f32x4)0.f; }
#pragma unroll
        for (int ks = 0; ks < 2; ++ks) {
            int koff = (ks * 64 + kg * 16);
            bf16x8 ac[2], as_[2], b[4];
#pragma unroll
            for (int mt = 0; mt < 2; ++mt) {
                int row = half * 32 + mt * 16 + pl;
                int off = row * 128 + (koff ^ ((pl & 7) << 4));
                ac[mt] = *(const bf16x8*)(tC + off);
                as_[mt] = *(const bf16x8*)(tS + off);
            }
#pragma unroll
            for (int nt = 0; nt < 4; ++nt) {
                int pos = wv * 64 + nt * 16 + pl;
                b[nt] = *(const bf16x8*)(xpT + pos * 128 + (koff ^ ((pl & 7) << 4)));
            }
#pragma unroll
            for (int mt = 0; mt < 2; ++mt)
#pragma unroll
                for (int nt = 0; nt < 4; ++nt) {
                    aR[mt][nt] = __builtin_amdgcn_mfma_f32_16x16x32_bf16(ac[mt], b[nt], aR[mt][nt], 0, 0, 0);
                    aI[mt][nt] = __builtin_amdgcn_mfma_f32_16x16x32_bf16(as_[mt], b[nt], aI[mt][nt], 0, 0, 0);
                }
        }
#pragma unroll
        for (int mt = 0; mt < 2; ++mt)
#pragma unroll
            for (int nt = 0; nt < 4; ++nt) {
                int c = nt * 16 + pl;
#pragma unroll
                for (int r = 0; r < 4; ++r) {
                    int fh = half * 32 + mt * 16 + kg * 4 + r;
                    Xw[fh * 64 + c] = packbf(aR[mt][nt][r], aI[mt][nt][r]);
                }
            }
    }
}

// ===========================================================================
// FUSED LRU mid-section: Bw-mix + bias + gamma + L-recurrence + Cw-mix.
// ===========================================================================
__global__ __launch_bounds__(256) void k_lrumid(unsigned int* __restrict__ X,
                                                const unsigned short* __restrict__ wbr,
                                                const unsigned short* __restrict__ wbi,
                                                const unsigned short* __restrict__ wcr,
                                                const unsigned short* __restrict__ wci,
                                                const float* __restrict__ gamT,
                                                const float* __restrict__ br_g,
                                                const float* __restrict__ bi_g,
                                                const float* __restrict__ plg) {
    __shared__ __align__(16) unsigned char smm[81920];
    unsigned char* inr = smm;
    unsigned char* ini = smm + 8192;
    unsigned char* hre = smm + 16384;
    unsigned char* him = smm + 24576;
    unsigned char* wBR = smm + 32768;
    unsigned char* wBI = smm + 40960;
    unsigned char* wCR = smm + 49152;
    unsigned char* wCI = smm + 57344;
    float* gam = (float*)(smm + 65536);
    int blk = blockIdx.x;
    int b = blk >> 6, s = blk & 63;
    int t = threadIdx.x, lane = t & 63, wv = t >> 6;
    int pj = lane & 15, kg = lane >> 4;
    int l3 = lane >> 3, l7 = lane & 7;

    for (int q = 0; q < 2; ++q) {
        int sg = q * 4 + wv;
        size_t goff = (size_t)(sg * 8 + l3) * 64 + (l7 ^ l3) * 8;
        gl2lds16(wbr + goff, wBR + sg * 1024);
        gl2lds16(wbi + goff, wBI + sg * 1024);
        gl2lds16(wcr + goff, wCR + sg * 1024);
        gl2lds16(wci + goff, wCI + sg * 1024);
    }
    for (int j = t; j < 4096; j += 256) gam[j] = gamT[j];

    float lamr[4][4], lami[4][4];
#pragma unroll
    for (int nt = 0; nt < 4; ++nt) {
        int o = nt * 16 + pj;
#pragma unroll
        for (int r = 0; r < 4; ++r) {
            int fh = wv * 16 + kg * 4 + r;
            float nu = expf(plg[o * 64 + fh]);
            float th = expf(plg[4096 + o * 64 + fh]);
            float mag = expf(-nu);
            float sth, cth;
            sincosf(th, &sth, &cth);
            lamr[nt][r] = mag * cth;
            lami[nt][r] = mag * sth;
        }
    }
    float bRo[4], bIo[4];
#pragma unroll
    for (int nt = 0; nt < 4; ++nt) {
        bRo[nt] = (s == 0) ? br_g[nt * 16 + pj] : 0.f;
        bIo[nt] = (s == 0) ? bi_g[nt * 16 + pj] : 0.f;
    }
    float str[4][4], sti[4][4];
    unsigned int* Xfrm = X + (size_t)b * 16 * 262144 + (size_t)s * 4096;

    for (int l = 0; l < 16; ++l) {
        unsigned int* Xi = Xfrm + (size_t)l * 262144;
        __syncthreads();
        for (int k = 0; k < 4; ++k) {
            int j = k * 256 + t;
            int row = j >> 4, c0 = (j & 15) * 4;
            u32x4 v = *(const u32x4*)(Xi + (size_t)row * 64 + c0);
            unsigned int rw0 = (v.x & 0xffffu) | (v.y << 16);
            unsigned int rw1 = (v.z & 0xffffu) | (v.w << 16);
            unsigned int iw0 = (v.x >> 16) | (v.y & 0xffff0000u);
            unsigned int iw1 = (v.z >> 16) | (v.w & 0xffff0000u);
            int off = row * 128 + ((((c0 >> 3) ^ (row & 7)) << 4) | ((c0 & 7) * 2));
            *(unsigned int*)(inr + off) = rw0;
            *(unsigned int*)(inr + off + 4) = rw1;
            *(unsigned int*)(ini + off) = iw0;
            *(unsigned int*)(ini + off + 4) = iw1;
        }
        __syncthreads();

        f32x4 cR[4], cI[4];
#pragma unroll
        for (int nt = 0; nt < 4; ++nt) { cR[nt] = (f32x4)0.f; cI[nt] = (f32x4)0.f; }
#pragma unroll
        for (int ks = 0; ks < 2; ++ks) {
            int koff = ks * 64 + kg * 16;
            int aoff = (wv * 16 + pj) * 128 + (koff ^ ((pj & 7) << 4));
            bf16x8 ar = *(const bf16x8*)(inr + aoff);
            bf16x8 ai = *(const bf16x8*)(ini + aoff);
            bf16x8 an = bneg(ai);
#pragma unroll
            for (int nt = 0; nt < 4; ++nt) {
                int o = nt * 16 + pj;
                int woff = o * 128 + (koff ^ ((pj & 7) << 4));
                bf16x8 brf = *(const bf16x8*)(wBR + woff);
                bf16x8 bif = *(const bf16x8*)(wBI + woff);
                cR[nt] = __builtin_amdgcn_mfma_f32_16x16x32_bf16(ar, brf, cR[nt], 0, 0, 0);
                cR[nt] = __builtin_amdgcn_mfma_f32_16x16x32_bf16(an, bif, cR[nt], 0, 0, 0);
                cI[nt] = __builtin_amdgcn_mfma_f32_16x16x32_bf16(ar, bif, cI[nt], 0, 0, 0);
                cI[nt] = __builtin_amdgcn_mfma_f32_16x16x32_bf16(ai, brf, cI[nt], 0, 0, 0);
            }
        }
#pragma unroll
        for (int nt = 0; nt < 4; ++nt) {
            int o = nt * 16 + pj;
#pragma unroll
            for (int r = 0; r < 4; ++r) {
                int row = wv * 16 + kg * 4 + r;
                float g = gam[row * 64 + o];
                float vr = (cR[nt][r] + bRo[nt]) * g;
                float vi = (cI[nt][r] + bIo[nt]) * g;
                if (l == 0) {
                    str[nt][r] = vr;
                    sti[nt][r] = vi;
                } else {
                    float nr = lamr[nt][r] * str[nt][r] - lami[nt][r] * sti[nt][r] + vr;
                    float ni = lamr[nt][r] * sti[nt][r] + lami[nt][r] * str[nt][r] + vi;
                    str[nt][r] = nr;
                    sti[nt][r] = ni;
                }
                int hoff = row * 128 + ((((o >> 3) ^ (row & 7)) << 4) | ((o & 7) * 2));
                *(unsigned short*)(hre + hoff) = bf16c(str[nt][r]);
                *(unsigned short*)(him + hoff) = bf16c(sti[nt][r]);
            }
        }
        __syncthreads();

        f32x4 dR[4], dI[4];
#pragma unroll
        for (int nt = 0; nt < 4; ++nt) { dR[nt] = (f32x4)0.f; dI[nt] = (f32x4)0.f; }
#pragma unroll
        for (int ks = 0; ks < 2; ++ks) {
            int koff = ks * 64 + kg * 16;
            int aoff = (wv * 16 + pj) * 128 + (koff ^ ((pj & 7) << 4));
            bf16x8 ar = *(const bf16x8*)(hre + aoff);
            bf16x8 ai = *(const bf16x8*)(him + aoff);
            bf16x8 an = bneg(ai);
#pragma unroll
            for (int nt = 0; nt < 4; ++nt) {
                int o = nt * 16 + pj;
                int woff = o * 128 + (koff ^ ((pj & 7) << 4));
                bf16x8 brf = *(const bf16x8*)(wCR + woff);
                bf16x8 bif = *(const bf16x8*)(wCI + woff);
                dR[nt] = __builtin_amdgcn_mfma_f32_16x16x32_bf16(ar, brf, dR[nt], 0, 0, 0);
                dR[nt] = __builtin_amdgcn_mfma_f32_16x16x32_bf16(an, bif, dR[nt], 0, 0, 0);
                dI[nt] = __builtin_amdgcn_mfma_f32_16x16x32_bf16(ar, bif, dI[nt], 0, 0, 0);
                dI[nt] = __builtin_amdgcn_mfma_f32_16x16x32_bf16(ai, brf, dI[nt], 0, 0, 0);
            }
        }
#pragma unroll
        for (int nt = 0; nt < 4; ++nt) {
            int o = nt * 16 + pj;
#pragma unroll
            for (int r = 0; r < 4; ++r) {
                int row = wv * 16 + kg * 4 + r;
                Xi[(size_t)row * 64 + o] = packbf(dR[nt][r], dI[nt][r]);
            }
        }
    }
}

// ===========================================================================
// Inverse DFT over h (Re only), MFMA + Cb + LayerNorm(H,W) + residual.
// ===========================================================================
__global__ __launch_bounds__(256) void k_idfthm_ln(const unsigned int* __restrict__ X,
                                                   const unsigned short* __restrict__ tic,
                                                   const unsigned short* __restrict__ tis,
                                                   const float* __restrict__ cbr,
                                                   const float* __restrict__ lnw,
                                                   const float* __restrict__ lnb,
                                                   const float* __restrict__ xprev,
                                                   float* __restrict__ xout) {
    __shared__ __align__(16) unsigned char smm[81920];
    unsigned char* SrT = smm;
    unsigned char* SiT = smm + 32768;
    unsigned char* tC = smm + 65536;
    unsigned char* tS = smm + 73728;
    float* y4 = (float*)smm;
    int blk = blockIdx.x;
    int fi = blk >> 4;
    int c0 = (blk & 15) * 4;
    int t = threadIdx.x, lane = t & 63, wv = t >> 6;
    int pl = lane & 15, kg = lane >> 4;
    int l3 = lane >> 3, l7 = lane & 7;

    for (int q = 0; q < 2; ++q) {
        int sg = q * 4 + wv;
        gl2lds16(tic + (size_t)(sg * 8 + l3) * 64 + (l7 ^ l3) * 8, tC + sg * 1024);
        gl2lds16(tis + (size_t)(sg * 8 + l3) * 64 + (l7 ^ l3) * 8, tS + sg * 1024);
    }
    const unsigned int* Xf = X + (size_t)fi * 262144;
    int fh = t & 63;
    for (int k = 0; k < 16; ++k) {
        int w = k * 4 + (t >> 6);
        u32x4 v = *(const u32x4*)(Xf + (size_t)w * 4096 + fh * 64 + c0);
        unsigned int vv[4] = {v.x, v.y, v.z, v.w};
#pragma unroll
        for (int cj = 0; cj < 4; ++cj) {
            int pos2 = w * 4 + cj;
            int off = pos2 * 128 + ((fh * 2) ^ ((pos2 & 7) << 4));
            *(unsigned short*)(SrT + off) = (unsigned short)(vv[cj] & 0xffffu);
            *(unsigned short*)(SiT + off) = (unsigned short)(vv[cj] >> 16);
        }
    }
    __syncthreads();

    f32x4 y[4][4];
#pragma unroll
    for (int mt = 0; mt < 4; ++mt)
#pragma unroll
        for (int nt = 0; nt < 4; ++nt) y[mt][nt] = (f32x4)0.f;
#pragma unroll
    for (int ks = 0; ks < 2; ++ks) {
        int koff = ks * 64 + kg * 16;
        bf16x8 ac[4], as_[4], brf[4], bif[4];
#pragma unroll
        for (int mt = 0; mt < 4; ++mt) {
            int row = mt * 16 + pl;
            int off = row * 128 + (koff ^ ((pl & 7) << 4));
            ac[mt] = *(const bf16x8*)(tC + off);
            as_[mt] = *(const bf16x8*)(tS + off);
        }
#pragma unroll
        for (int nt = 0; nt < 4; ++nt) {
            int pos2 = wv * 64 + nt * 16 + pl;
            int off = pos2 * 128 + (koff ^ ((pl & 7) << 4));
            brf[nt] = *(const bf16x8*)(SrT + off);
            bif[nt] = *(const bf16x8*)(SiT + off);
        }
#pragma unroll
        for (int mt = 0; mt < 4; ++mt)
#pragma unroll
            for (int nt = 0; nt < 4; ++nt) {
                y[mt][nt] = __builtin_amdgcn_mfma_f32_16x16x32_bf16(ac[mt], brf[nt], y[mt][nt], 0, 0, 0);
                y[mt][nt] = __builtin_amdgcn_mfma_f32_16x16x32_bf16(as_[mt], bif[nt], y[mt][nt], 0, 0, 0);
            }
    }
    __syncthreads();

    float cb4[4];
#pragma unroll
    for (int cj = 0; cj < 4; ++cj) cb4[cj] = cbr[c0 + cj];
#pragma unroll
    for (int mt = 0; mt < 4; ++mt)
#pragma unroll
        for (int nt = 0; nt < 4; ++nt) {
            int pos2 = wv * 64 + nt * 16 + pl;
            int w = pos2 >> 2, cj = pos2 & 3;
#pragma unroll
            for (int r = 0; r < 4; ++r) {
                int h = mt * 16 + kg * 4 + r;
                y4[cj * 4232 + h * 66 + w] = y[mt][nt][r] + cb4[cj];
            }
        }
    __syncthreads();

    int w = lane;
    const float* yp = y4 + wv * 4232;
    float s = 0.f, q = 0.f;
    for (int h = 0; h < 64; ++h) {
        float v = yp[h * 66 + w];
        s += v;
        q += v * v;
    }
#pragma unroll
    for (int off = 32; off; off >>= 1) {
        s += __shfl_xor(s, off);
        q += __shfl_xor(q, off);
    }
    float m = s * (1.f / 4096.f);
    float var = q * (1.f / 4096.f) - m * m;
    float rs = rsqrtf(var + 1e-5f);
    int c = c0 + wv;
    const float* xp = xprev + ((size_t)fi * Cd + c) * HW;
    float* xo = xout + ((size_t)fi * Cd + c) * HW;
    for (int h = 0; h < 64; ++h) {
        int p = h * 64 + w;
        xo[p] = (yp[h * 66 + w] - m) * rs * lnw[p] + lnb[p] + xp[p];
    }
}

// ===========================================================================
// LN(H,W) + residual accumulate, channel-planar (final ffn_ln). cobuf bf16.
// ===========================================================================
__global__ __launch_bounds__(256) void k_ln_res(const unsigned short* __restrict__ t_in,
                                                const float* __restrict__ w,
                                                const float* __restrict__ b,
                                                float* __restrict__ dst) {
    __shared__ float red[8];
    int fr = blockIdx.x;
    int t = threadIdx.x;
    const unsigned short* src = t_in + (size_t)fr * HW + t * 16;
    float* d = dst + (size_t)fr * HW + t * 16;
    u32x4 v0 = *(const u32x4*)(src);
    u32x4 v1 = *(const u32x4*)(src + 8);
    float vals[16];
    unsigned int vw[8] = {v0.x, v0.y, v0.z, v0.w, v1.x, v1.y, v1.z, v1.w};
#pragma unroll
    for (int j = 0; j < 8; ++j) {
        vals[j * 2] = bf2f((unsigned short)(vw[j] & 0xffffu));
        vals[j * 2 + 1] = bf2f((unsigned short)(vw[j] >> 16));
    }
    float s = 0.f, sq = 0.f;
#pragma unroll
    for (int j = 0; j < 16; ++j) { s += vals[j]; sq += vals[j] * vals[j]; }
    for (int off = 32; off; off >>= 1) {
        s += __shfl_down(s, off);
        sq += __shfl_down(sq, off);
    }
    int wid = t >> 6;
    if ((t & 63) == 0) { red[wid] = s; red[4 + wid] = sq; }
    __syncthreads();
    s = red[0] + red[1] + red[2] + red[3];
    sq = red[4] + red[5] + red[6] + red[7];
    float m = s * (1.f / 4096.f);
    float var = sq * (1.f / 4096.f) - m * m;
    float rs = rsqrtf(var + 1e-5f);
    const float* wp = w + t * 16;
    const float* bp = b + t * 16;
#pragma unroll
    for (int q4 = 0; q4 < 4; ++q4) {
        float4 wv4 = *(const float4*)(wp + q4 * 4);
        float4 bv4 = *(const float4*)(bp + q4 * 4);
        float4 dv = *(const float4*)(d + q4 * 4);
        dv.x += (vals[q4 * 4 + 0] - m) * rs * wv4.x + bv4.x;
        dv.y += (vals[q4 * 4 + 1] - m) * rs * wv4.y + bv4.y;
        dv.z += (vals[q4 * 4 + 2] - m) * rs * wv4.z + bv4.z;
        dv.w += (vals[q4 * 4 + 3] - m) * rs * wv4.w + bv4.w;
        *(float4*)(d + q4 * 4) = dv;
    }
}

// ===========================================================================
// Weight prep (fp32 -> bf16, MFMA-friendly layouts)
// ===========================================================================
__global__ void k_prep7(const float* __restrict__ w, unsigned short* __restrict__ o) {
    int idx = blockIdx.x * 256 + threadIdx.x;     // tap*8192 + f*64 + c
    if (idx < 49 * 128 * 64) {
        int tap = idx >> 13, rem = idx & 8191, f = rem >> 6, c = rem & 63;
        o[idx] = bf16c(w[(size_t)(f * 64 + c) * 49 + tap]);
    }
}
__global__ void k_prep3(const float* __restrict__ w, unsigned short* __restrict__ o,
                        int nh) {
    int idx = blockIdx.x * 256 + threadIdx.x;
    if (idx < nh * 147456) {
        int head = idx / 147456;
        int rem = idx - head * 147456;
        int tap = rem >> 14, r2 = rem & 16383, f = r2 >> 7, c = r2 & 127;
        o[idx] = bf16c(w[(size_t)head * 147456 + (size_t)(f * 128 + c) * 9 + tap]);
    }
}
__global__ void k_prepcvt(const float* __restrict__ w, unsigned short* __restrict__ o, int n) {
    int idx = blockIdx.x * 256 + threadIdx.x;
    if (idx < n) o[idx] = bf16c(w[idx]);
}

// Channel-planar fp32 -> position-major bf16  ([c][HW] -> [pos][64])
__global__ __launch_bounds__(256) void k_t2p(const float* __restrict__ x,
                                             unsigned short* __restrict__ xT) {
    __shared__ float tile[64][65];
    int blk = blockIdx.x;
    int f = blk >> 6;
    int p0 = (blk & 63) * 64;
    int t = threadIdx.x;
    const float* src = x + (size_t)f * Cd * HW;
    for (int j = t; j < 4096; j += 256) {
        int c = j >> 6, p = j & 63;
        tile[c][p] = src[(size_t)c * HW + p0 + p];
    }
    __syncthreads();
    unsigned short* dst = xT + ((size_t)f * HW + p0) * 64;
    for (int j = t; j < 4096; j += 256) {
        int p = j >> 6, c = j & 63;
        dst[(size_t)p * 64 + c] = bf16c(tile[c][p]);
    }
}

// ===========================================================================
// 7x7 conv, MFMA 16x16x32, XOR-swizzled LDS. 8 waves, 8 output rows/block.
// (round-15 proven version: 175 us, zero bank conflicts)
// ===========================================================================
__global__ __launch_bounds__(512) void k_conv7m(const unsigned short* __restrict__ xT,
                                                const unsigned short* __restrict__ wb,
                                                const float* __restrict__ bias,
                                                unsigned short* __restrict__ yout) {
    __shared__ __align__(16) unsigned char smm[158208];   // inT 14*8960 | wdbuf 2*16384
    unsigned char* inT = smm;
    unsigned char* wt0 = smm + 125440;
    int blk = blockIdx.x;
    int fi = blk >> 3;
    int y0 = (blk & 7) * 8;
    int t = threadIdx.x, lane = t & 63, wv = t >> 6;
    int l3 = lane >> 3, l7 = lane & 7;

    const unsigned short* xf = xT + (size_t)fi * HW * 64;
    float4 z4 = make_float4(0.f, 0.f, 0.f, 0.f);
    int ksw_in = l7 ^ ((3 + l3) & 7);
    for (int idx = wv; idx < 112; idx += 8) {
        int r = idx >> 3, sg = idx & 7;
        int srow = y0 + r - 3;
        unsigned char* dst = inT + r * 8960 + 3 * 128 + sg * 1024;
        if (srow >= 0 && srow < 64) {
            gl2lds16(xf + (size_t)srow * 4096 + (sg * 8 + l3) * 64 + ksw_in * 8, dst);
        } else {
            *(float4*)(dst + lane * 16) = z4;
        }
    }
    for (int j = t; j < 672; j += 512) {
        int r = j / 48, k = j % 48;
        int xp = (k < 24) ? (k >> 3) : 67 + ((k - 24) >> 3);
        *(float4*)(inT + r * 8960 + xp * 128 + (k & 7) * 16) = z4;
    }
    int ksw_w = l7 ^ l3;
    for (int q = 0; q < 2; ++q) {
        int sg = q * 8 + wv;
        int f = sg * 8 + l3;
        gl2lds16(wb + (size_t)f * 64 + ksw_w * 8, wt0 + sg * 1024);
    }
    __syncthreads();

    int wm = wv & 3, wn = wv >> 2;
    f32x4 acc[8][4];
#pragma unroll
    for (int m = 0; m < 8; ++m)
#pragma unroll
        for (int n = 0; n < 4; ++n) acc[m][n] = (f32x4)0.f;
    int kg = lane >> 4, pl = lane & 15;
    int cur = 0;
    for (int tap = 0; tap < 49; ++tap) {
        if (tap + 1 < 49) {
            const unsigned short* g = wb + (size_t)(tap + 1) * 8192;
            unsigned char* wdst = wt0 + (cur ^ 1) * 16384;
            for (int q = 0; q < 2; ++q) {
                int sg = q * 8 + wv;
                int f = sg * 8 + l3;
                gl2lds16(g + (size_t)f * 64 + ksw_w * 8, wdst + sg * 1024);
            }
        }
        unsigned char* wcur = wt0 + cur * 16384;
        int ky = tap / 7, kx = tap % 7;
#pragma unroll
        for (int ks = 0; ks < 2; ++ks) {
            bf16x8 a[8], b[4];
#pragma unroll
            for (int m = 0; m < 8; ++m) {
                int row = wm * 2 + (m >> 2) + ky;
                int xp = (m & 3) * 16 + pl + kx;
                a[m] = *(const bf16x8*)(inT + row * 8960 + xp * 128 +
                                        (((ks * 4 + kg) ^ (xp & 7)) << 4));
            }
#pragma unroll
            for (int n = 0; n < 4; ++n) {
                int rowf = wn * 64 + n * 16 + pl;
                b[n] = *(const bf16x8*)(wcur + rowf * 128 +
                                        (((ks * 4 + kg) ^ (pl & 7)) << 4));
            }
#pragma unroll
            for (int m = 0; m < 8; ++m)
#pragma unroll
                for (int n = 0; n < 4; ++n)
                    acc[m][n] = __builtin_amdgcn_mfma_f32_16x16x32_bf16(a[m], b[n], acc[m][n], 0, 0, 0);
        }
        __syncthreads();
        cur ^= 1;
    }
    unsigned short* yo = yout + ((size_t)fi * HW + (size_t)y0 * 64) * 128;
#pragma unroll
    for (int m = 0; m < 8; ++m) {
        int rowl = wm * 2 + (m >> 2);
#pragma unroll
        for (int n = 0; n < 4; ++n) {
            int f = wn * 64 + n * 16 + pl;
            float bs = bias[f];
#pragma unroll
            for (int r = 0; r < 4; ++r) {
                int x = (m & 3) * 16 + kg * 4 + r;
                yo[(size_t)(rowl * 64 + x) * 128 + f] = bf16c(gelu_f(acc[m][n][r] + bs));
            }
        }
    }
}

// ===========================================================================
// FUSED 3x3 conv + 1x1 (h1) + gelu + LN partials. 8 waves, 4 rows/block.
// conv7m-style: no pad columns (edge via compile-time predicated selects),
// 2x32KB DMA double-buffered weights, ONE barrier per tap (9 total).
// ===========================================================================
__global__ __launch_bounds__(512) void k_conv3f(const unsigned short* __restrict__ yin,
                                                const unsigned short* __restrict__ wb,
                                                const float* __restrict__ bias3,
                                                const unsigned short* __restrict__ w1,
                                                const float* __restrict__ bias1,
                                                unsigned short* __restrict__ outp2,
                                                float* __restrict__ lnpart) {
    __shared__ __align__(16) unsigned char smm[163840];   // inT 98304 | wdbuf 2*32768
    unsigned char* inT = smm;
    unsigned char* wt0 = smm + 98304;
    int blk = blockIdx.x;
    int fi = blk >> 4;
    int y0 = (blk & 15) * 4;
    int t = threadIdx.x, lane = t & 63, wv = t >> 6;
    int l4 = lane >> 4, l15 = lane & 15;
    const unsigned short* yf = yin + (size_t)fi * HW * 128;
    float4 z4 = make_float4(0.f, 0.f, 0.f, 0.f);
    // stage 6 input rows (y0-1 .. y0+4), cols 0..63, no pads
    for (int seg = wv; seg < 96; seg += 8) {
        int r = seg >> 4, xs = seg & 15;
        int srow = y0 + r - 1;
        int col = xs * 4 + l4;
        unsigned char* dst = inT + r * 16384 + xs * 4 * 256;
        if (srow >= 0 && srow < 64) {
            int gs = l15 ^ (col & 7);
            gl2lds16(yf + ((size_t)(srow * 64 + col) * 128 + gs * 8), dst);
        } else {
            *(float4*)(dst + lane * 16) = z4;
        }
    }
    // weights tap 0
    for (int q = 0; q < 4; ++q) {
        int sg = q * 8 + wv;
        int f = sg * 4 + l4;
        gl2lds16(wb + (size_t)f * 128 + (l15 ^ (f & 7)) * 8, wt0 + sg * 1024);
    }
    __syncthreads();

    int wm = wv & 3, wn = wv >> 2;
    f32x4 acc[4][4];
#pragma unroll
    for (int m = 0; m < 4; ++m)
#pragma unroll
        for (int n = 0; n < 4; ++n) acc[m][n] = (f32x4)0.f;
    int kg = lane >> 4, pl = lane & 15;
    bf16x8 z8 = (bf16x8)(short)0;
    int cur = 0;
#pragma unroll
    for (int tap = 0; tap < 9; ++tap) {
        if (tap + 1 < 9) {
            const unsigned short* g = wb + (size_t)(tap + 1) * 16384;
            unsigned char* wdst = wt0 + (cur ^ 1) * 32768;
            for (int q = 0; q < 4; ++q) {
                int sg = q * 8 + wv;
                int f = sg * 4 + l4;
                gl2lds16(g + (size_t)f * 128 + (l15 ^ (f & 7)) * 8, wdst + sg * 1024);
            }
        }
        unsigned char* wcur = wt0 + cur * 32768;
        const int ky = tap / 3, kx = tap % 3;
        int rbase = (wm + ky) * 16384;
#pragma unroll
        for (int ks = 0; ks < 4; ++ks) {
            bf16x8 a[4], b[4];
#pragma unroll
            for (int m = 0; m < 4; ++m) {
                int col = m * 16 + pl + kx - 1;
                int colc = col;
                if (kx == 0 && m == 0) colc = (col < 0) ? 0 : col;
                if (kx == 2 && m == 3) colc = (col > 63) ? 63 : col;
                a[m] = *(const bf16x8*)(inT + rbase + colc * 256 +
                                        ((ks * 64 + kg * 16) ^ ((colc & 7) << 4)));
                if (kx == 0 && m == 0) a[m] = (pl == 0) ? z8 : a[m];
                if (kx == 2 && m == 3) a[m] = (pl == 15) ? z8 : a[m];
            }
#pragma unroll
            for (int n = 0; n < 4; ++n) {
                int row = wn * 64 + n * 16 + pl;
                b[n] = *(const bf16x8*)(wcur + (size_t)row * 256 +
                                        ((ks * 64 + kg * 16) ^ ((pl & 7) << 4)));
            }
#pragma unroll
            for (int m = 0; m < 4; ++m)
#pragma unroll
                for (int n = 0; n < 4; ++n)
                    acc[m][n] = __builtin_amdgcn_mfma_f32_16x16x32_bf16(a[m], b[n], acc[m][n], 0, 0, 0);
        }
        __syncthreads();
        cur ^= 1;
    }

    // ---- fused 1x1: t -> LDS (inT region dead), stage W1, GEMM ----
    unsigned char* tL = smm;              // [256 pos][128 f] bf16, swz (64K)
    unsigned char* w1L = smm + 65536;     // [128 o][128 f] bf16, swz (32K)
    float (*redS)[64] = (float (*)[64])(smm + 155648);
    float (*redQ)[64] = (float (*)[64])(smm + 157696);
#pragma unroll
    for (int m = 0; m < 4; ++m)
#pragma unroll
        for (int n = 0; n < 4; ++n) {
            int f = wn * 64 + n * 16 + pl;
            float bs = bias3[f];
#pragma unroll
            for (int r = 0; r < 4; ++r) {
                int pos = wm * 64 + m * 16 + kg * 4 + r;
                *(unsigned short*)(tL + (size_t)pos * 256 +
                    ((((f >> 3) ^ (pos & 7)) << 4) | ((f & 7) * 2))) =
                    bf16c(gelu_f(acc[m][n][r] + bs));
            }
        }
    for (int sg = wv; sg < 32; sg += 8) {
        int rr = sg * 4 + l4;
        gl2lds16(w1 + (size_t)rr * 128 + (l15 ^ (rr & 7)) * 8, w1L + sg * 1024);
    }
    __syncthreads();

    f32x4 fa[4][4];
#pragma unroll
    for (int m = 0; m < 4; ++m)
#pragma unroll
        for (int n = 0; n < 4; ++n) fa[m][n] = (f32x4)0.f;
#pragma unroll
    for (int ks = 0; ks < 4; ++ks) {
        bf16x8 a[4], b[4];
#pragma unroll
        for (int m = 0; m < 4; ++m) {
            int row = wm * 64 + m * 16 + pl;
            a[m] = *(const bf16x8*)(tL + (size_t)row * 256 +
                                    ((ks * 64 + kg * 16) ^ ((pl & 7) << 4)));
        }
#pragma unroll
        for (int n = 0; n < 4; ++n) {
            int row = wn * 64 + n * 16 + pl;
            b[n] = *(const bf16x8*)(w1L + (size_t)row * 256 +
                                    ((ks * 64 + kg * 16) ^ ((pl & 7) << 4)));
        }
#pragma unroll
        for (int m = 0; m < 4; ++m)
#pragma unroll
            for (int n = 0; n < 4; ++n)
                fa[m][n] = __builtin_amdgcn_mfma_f32_16x16x32_bf16(a[m], b[n], fa[m][n], 0, 0, 0);
    }
    __syncthreads();

    int slab = blk & 15;
    int p0 = slab * 256;
    unsigned char* oL = smm;
#pragma unroll
    for (int n = 0; n < 4; ++n) {
        int f = wn * 64 + n * 16 + pl;
        float bs = bias1[f];
        float s = 0.f, q = 0.f;
#pragma unroll
        for (int m = 0; m < 4; ++m)
#pragma unroll
            for (int r = 0; r < 4; ++r) {
                float v = gelu_f(fa[m][n][r] + bs);
                int pos = wm * 64 + m * 16 + kg * 4 + r;
                *(unsigned short*)(oL + (size_t)pos * 256 +
                    ((((f >> 3) ^ (pos & 7)) << 4) | ((f & 7) * 2))) = bf16c(v);
                s += v;
                q += v * v;
            }
        s += __shfl_xor(s, 16); s += __shfl_xor(s, 32);
        q += __shfl_xor(q, 16); q += __shfl_xor(q, 32);
        if (kg == 0) { redS[wv][n * 16 + pl] = s; redQ[wv][n * 16 + pl] = q; }
    }
    __syncthreads();
    unsigned char* o0 = (unsigned char*)(outp2 + ((size_t)fi * HW + p0) * 128);
#pragma unroll
    for (int it = 0; it < 8; ++it) {
        int gid = it * 512 + t;
        int pos = gid >> 4, g = gid & 15;
        u32x4 v = *(const u32x4*)(oL + (size_t)pos * 256 + ((g ^ (pos & 7)) << 4));
        *(u32x4*)(o0 + (size_t)pos * 256 + g * 16) = v;
    }
    if (t < 128) {
        int wh = t >> 6, j = t & 63;
        float s = redS[wh * 4][j] + redS[wh * 4 + 1][j] + redS[wh * 4 + 2][j] + redS[wh * 4 + 3][j];
        float q = redQ[wh * 4][j] + redQ[wh * 4 + 1][j] + redQ[wh * 4 + 2][j] + redQ[wh * 4 + 3][j];
        float* lp = lnpart + ((size_t)(fi * 16 + slab) * 128 + t) * 2;
        lp[0] = s;
        lp[1] = q;
    }
}

// ===========================================================================
// LN finalize (16 slab partials) + apply: y += LN(t2)*w + b. t2, y bf16.
// Vectorized: each thread owns 8 consecutive f (u32x4 per access).
// ===========================================================================
__global__ __launch_bounds__(256) void k_lnapply2(const unsigned short* __restrict__ t2,
                                                  const float* __restrict__ lnpart,
                                                  const float* __restrict__ w,
                                                  const float* __restrict__ b,
                                                  unsigned short* __restrict__ y) {
    __shared__ float sm_m[128], sm_r[128];
    int blk = blockIdx.x;
    int fi = blk >> 5, p0 = (blk & 31) * 128;
    int t = threadIdx.x;
    if (t < 128) {
        float s = 0.f, q = 0.f;
        for (int sl = 0; sl < 16; ++sl) {
            const float* lp = lnpart + ((size_t)(fi * 16 + sl) * 128 + t) * 2;
            s += lp[0];
            q += lp[1];
        }
        float m = s * (1.f / 4096.f);
        float var = q * (1.f / 4096.f) - m * m;
        sm_m[t] = m;
        sm_r[t] = rsqrtf(var + 1e-5f);
    }
    __syncthreads();
    int f0 = (t & 15) * 8, prow = t >> 4;
    float mm[8], rr[8];
#pragma unroll
    for (int j = 0; j < 8; ++j) { mm[j] = sm_m[f0 + j]; rr[j] = sm_r[f0 + j]; }
#pragma unroll
    for (int pass = 0; pass < 8; ++pass) {
        int p = p0 + pass * 16 + prow;
        size_t idx = ((size_t)fi * HW + p) * 128 + f0;
        u32x4 tv = *(const u32x4*)(t2 + idx);
        u32x4 yv = *(const u32x4*)(y + idx);
        float wp = w[p], bp = b[p];
        unsigned int tw[4] = {tv.x, tv.y, tv.z, tv.w};
        unsigned int yw[4] = {yv.x, yv.y, yv.z, yv.w};
        unsigned int ow[4];
#pragma unroll
        for (int q4 = 0; q4 < 4; ++q4) {
            float t0 = bf2f((unsigned short)(tw[q4] & 0xffffu));
            float t1 = bf2f((unsigned short)(tw[q4] >> 16));
            float y0 = bf2f((unsigned short)(yw[q4] & 0xffffu));
            float y1 = bf2f((unsigned short)(yw[q4] >> 16));
            float o0 = y0 + (t0 - mm[q4 * 2]) * rr[q4 * 2] * wp + bp;
            float o1 = y1 + (t1 - mm[q4 * 2 + 1]) * rr[q4 * 2 + 1] * wp + bp;
            ow[q4] = packbf(o0, o1);
        }
        u32x4 ov;
        ov.x = ow[0]; ov.y = ow[1]; ov.z = ow[2]; ov.w = ow[3];
        *(u32x4*)(y + idx) = ov;
    }
}

// ===========================================================================
// 1x1 cout (128->64), MFMA, A=weights -> channel-planar bf16 out via LDS
// repack -> coalesced stores. y bf16 in.
// ===========================================================================
__global__ __launch_bounds__(256) void k_coutm(const unsigned short* __restrict__ yin,
                                               const unsigned short* __restrict__ wt,
                                               const float* __restrict__ bias,
                                               unsigned short* __restrict__ outp) {
    __shared__ __align__(16) unsigned char smm[49152];
    unsigned char* inL = smm;
    unsigned char* wL = smm + 32768;
    int blk = blockIdx.x;
    int fi = blk >> 5;
    int p0 = (blk & 31) * 128;
    int t = threadIdx.x, lane = t & 63, wv = t >> 6;
    int l4 = lane >> 4, l15 = lane & 15;
    for (int sg = wv; sg < 16; sg += 4) {
        int r = sg * 4 + l4;
        gl2lds16(wt + (size_t)r * 128 + (l15 ^ (r & 7)) * 8, wL + sg * 1024);
    }
    const unsigned short* yb = yin + (size_t)fi * HW * 128;
    for (int sg = wv; sg < 32; sg += 4) {
        int pos = sg * 4 + l4;
        gl2lds16(yb + ((size_t)(p0 + pos) * 128 + (l15 ^ (pos & 7)) * 8), inL + sg * 1024);
    }
    __syncthreads();
    int wm = wv & 1, wn = wv >> 1;
    f32x4 acc[2][4];
#pragma unroll
    for (int m = 0; m < 2; ++m)
#pragma unroll
        for (int n = 0; n < 4; ++n) acc[m][n] = (f32x4)0.f;
    int kg = lane >> 4, pl = lane & 15;
#pragma unroll
    for (int ks = 0; ks < 4; ++ks) {
        bf16x8 a[2], b[4];
#pragma unroll
        for (int m = 0; m < 2; ++m) {
            int row = wm * 32 + m * 16 + pl;
            a[m] = *(const bf16x8*)(wL + (size_t)row * 256 +
                                    ((ks * 64 + kg * 16) ^ ((pl & 7) << 4)));
        }
#pragma unroll
        for (int n = 0; n < 4; ++n) {
            int row = wn * 64 + n * 16 + pl;
            b[n] = *(const bf16x8*)(inL + (size_t)row * 256 +
                                    ((ks * 64 + kg * 16) ^ ((pl & 7) << 4)));
        }
#pragma unroll
        for (int m = 0; m < 2; ++m)
#pragma unroll
            for (int n = 0; n < 4; ++n)
                acc[m][n] = __builtin_amdgcn_mfma_f32_16x16x32_bf16(a[m], b[n], acc[m][n], 0, 0, 0);
    }
    __syncthreads();
    unsigned char* oL = smm;
#pragma unroll
    for (int m = 0; m < 2; ++m)
#pragma unroll
        for (int n = 0; n < 4; ++n) {
            int posl = wn * 64 + n * 16 + pl;
#pragma unroll
            for (int r = 0; r < 4; ++r) {
                int c = wm * 32 + m * 16 + kg * 4 + r;
                *(unsigned short*)(oL + (size_t)c * 256 +
                    ((((posl >> 3) ^ (c & 7)) << 4) | ((posl & 7) * 2))) =
                    bf16c(acc[m][n][r] + bias[c]);
            }
        }
    __syncthreads();
#pragma unroll
    for (int it = 0; it < 4; ++it) {
        int gid = it * 256 + t;
        int c = gid >> 4, g = gid & 15;
        u32x4 v = *(const u32x4*)(oL + (size_t)c * 256 + ((g ^ (c & 7)) << 4));
        *(u32x4*)((unsigned char*)(outp + ((size_t)fi * 64 + c) * HW + p0) + g * 16) = v;
    }
}

// ===========================================================================
extern "C" void kernel_launch(void* const* d_in, const int* in_sizes, int n_in,
                              void* d_out, int out_size, void* d_ws, size_t ws_size,
                              hipStream_t stream) {
    (void)in_sizes; (void)n_in; (void)out_size;
    const float* x_in  = (const float*)d_in[0];
    const float* pl    = (const float*)d_in[1];
    const float* pBw_r = (const float*)d_in[2];
    const float* pBw_i = (const float*)d_in[3];
    const float* pBb_r = (const float*)d_in[4];
    const float* pBb_i = (const float*)d_in[5];
    const float* pCw_r = (const float*)d_in[6];
    const float* pCw_i = (const float*)d_in[7];
    const float* pCb_r = (const float*)d_in[8];
    const float* pCb_i = (const float*)d_in[9];
    const float* lruw  = (const float*)d_in[10];
    const float* lrub  = (const float*)d_in[11];
    const float* cinw  = (const float*)d_in[12];
    const float* cinb  = (const float*)d_in[13];
    const float* h3w   = (const float*)d_in[14];
    const float* h3b   = (const float*)d_in[15];
    const float* h1w   = (const float*)d_in[16];
    const float* h1b   = (const float*)d_in[17];
    const float* hlnw  = (const float*)d_in[18];
    const float* hlnb  = (const float*)d_in[19];
    const float* coutw = (const float*)d_in[20];
    const float* coutb = (const float*)d_in[21];
    const float* flnw  = (const float*)d_in[22];
    const float* flnb  = (const float*)d_in[23];
    float* out = (float*)d_out;

    // --- adaptive chunk tier (X bf16: 16.78 MB per LRU batch; FFN 3 MiB/frame) ---
    int FR = 8, LB = 1;
    {
        const int frs[6] = {64, 32, 16, 16, 8, 8};
        const int lbs[6] = {4, 4, 4, 2, 2, 1};
        for (int k = 0; k < 6; ++k) {
            size_t region = (size_t)lbs[k] * 16777216ULL;
            size_t ffn = (size_t)frs[k] * 3145728ULL;
            if (ffn > region) region = ffn;
            size_t needb = region + 1605632ULL + (size_t)frs[k] * 32768ULL + 65536ULL;
            if (needb <= ws_size) { FR = frs[k]; LB = lbs[k]; break; }
        }
    }
    size_t region = (size_t)LB * 16777216ULL;
    {
        size_t ffn = (size_t)FR * 3145728ULL;
        if (ffn > region) region = ffn;
    }
    unsigned char* ws = (unsigned char*)d_ws;
    unsigned int* Xb = (unsigned int*)ws;                                // LB*16.78 MB
    unsigned short* ybuf = (unsigned short*)ws;                          // FR*1 MiB
    unsigned short* t2bf = (unsigned short*)(ws + (size_t)FR * 1048576); // FR*1 MiB
    unsigned short* xT   = (unsigned short*)(ws + (size_t)FR * 2097152); // FR*0.5 MiB
    unsigned short* cobuf = (unsigned short*)(ws + (size_t)FR * 2621440);// FR*0.5 MiB
    unsigned char* wbase = ws + region;
    unsigned short* wb7  = (unsigned short*)(wbase);              //   802,816 B
    unsigned short* wb3  = (unsigned short*)(wbase + 802816);     //   589,824 B
    unsigned short* wb1  = (unsigned short*)(wbase + 1392640);    //    65,536 B
    unsigned short* wbco = (unsigned short*)(wbase + 1458176);    //    16,384 B
    unsigned short* dftT = (unsigned short*)(wbase + 1474560);    //    32,768 B
    unsigned short* lruW = (unsigned short*)(wbase + 1507328);    //    32,768 B
    float* gamT          = (float*)(wbase + 1540096);             //    16,384 B
    float* lnpart        = (float*)(wbase + 1556480);             // FR*32,768 B
    unsigned short* tcb = dftT;
    unsigned short* tsb = dftT + 4096;
    unsigned short* tic = dftT + 8192;
    unsigned short* tis = dftT + 12288;
    unsigned short* wBr = lruW;
    unsigned short* wBi = lruW + 4096;
    unsigned short* wCr = lruW + 8192;
    unsigned short* wCi = lruW + 12288;

    const int NCl = 4 / LB;
    const int NCf = 64 / FR;

    k_prepdft<<<64, 256, 0, stream>>>(dftT);

    for (int i = 0; i < NBLK; ++i) {
        const float* xsrc = (i == 0) ? x_in : out;

        // ---------------- ConvLRULayer (MFMA, half-domain DFT over h) -------
        k_preplru<<<80, 256, 0, stream>>>(pBw_r + (size_t)i * 4096,
                                          pBw_i + (size_t)i * 4096,
                                          pCw_r + (size_t)i * 4096,
                                          pCw_i + (size_t)i * 4096,
                                          pl + (size_t)i * 12288 + 8192, lruW, gamT);
        for (int cc = 0; cc < NCl; ++cc) {
            size_t boff = (size_t)cc * LB * 4194304;
            k_dfthm<<<LB * 256, 256, 0, stream>>>(xsrc + boff, Xb, tcb, tsb);
            k_lrumid<<<LB * 64, 256, 0, stream>>>(Xb, wBr, wBi, wCr, wCi, gamT,
                                                  pBb_r + (size_t)i * 64,
                                                  pBb_i + (size_t)i * 64,
                                                  pl + (size_t)i * 12288);
            k_idfthm_ln<<<LB * 256, 256, 0, stream>>>(Xb, tic, tis,
                                                      pCb_r + (size_t)i * 64,
                                                      lruw + (size_t)i * 4096,
                                                      lrub + (size_t)i * 4096,
                                                      xsrc + boff, out + boff);
        }

        // ---------------- FFN weight prep ----------------
        k_prep7<<<1568, 256, 0, stream>>>(cinw + (size_t)i * 401408, wb7);
        k_prep3<<<1152, 256, 0, stream>>>(h3w + (size_t)i * 2 * 147456, wb3, 2);
        k_prepcvt<<<128, 256, 0, stream>>>(h1w + (size_t)i * 2 * 16384, wb1, 32768);
        k_prepcvt<<<32, 256, 0, stream>>>(coutw + (size_t)i * 8192, wbco, 8192);

        // ---------------- FeedForward (FR-frame chunks) ----------------
        for (int cc = 0; cc < NCf; ++cc) {
            float* xb = out + (size_t)cc * FR * 262144;
            k_t2p<<<FR * 64, 256, 0, stream>>>(xb, xT);
            k_conv7m<<<FR * 8, 512, 0, stream>>>(xT, wb7, cinb + (size_t)i * 128, ybuf);
            for (int j = 0; j < NHEAD; ++j) {
                k_conv3f<<<FR * 16, 512, 0, stream>>>(ybuf, wb3 + (size_t)j * 147456,
                                                      h3b + (size_t)(i * 2 + j) * 128,
                                                      wb1 + (size_t)j * 16384,
                                                      h1b + (size_t)(i * 2 + j) * 128,
                                                      t2bf, lnpart);
                k_lnapply2<<<FR * 32, 256, 0, stream>>>(t2bf, lnpart,
                                                        hlnw + (size_t)(i * 2 + j) * 4096,
                                                        hlnb + (size_t)(i * 2 + j) * 4096,
                                                        ybuf);
            }
            k_coutm<<<FR * 32, 256, 0, stream>>>(ybuf, wbco, coutb + (size_t)i * 64, cobuf);
            k_ln_res<<<FR * 64, 256, 0, stream>>>(cobuf, flnw + (size_t)i * 4096,
                                                  flnb + (size_t)i * 4096, xb);
        }
    }
}